// Round 11
// baseline (516.799 us; speedup 1.0000x reference)
//
#include <hip/hip_runtime.h>
#include <hip/hip_bf16.h>

// Problem constants
#define HH 64
#define WW 128
#define DD 48
#define CG 8
// Padded volume layout: [d 50][w 130][h 66][c 32]  (channels-last, h inner)
#define PD 50
#define PWp 130
#define PHp 66
#define ROW 2112                               // elems per (d,w) row = 66*32
#define PVOL ((size_t)PD * PWp * ROW)          // 13,728,000 elems
#define FEAT ((size_t)HH * WW * 256)
#define SLICE_E (6 * ROW)                      // 12672 elems = 25344 B
#define NBLK 512u                              // conv grid: all-resident (2/CU)

typedef __hip_bfloat16 bf16;
typedef __attribute__((ext_vector_type(8))) short short8;
typedef __attribute__((ext_vector_type(4))) float f32x4;

__device__ __forceinline__ void gload_lds16(const bf16* g, bf16* l) {
    __builtin_amdgcn_global_load_lds(
        (const __attribute__((address_space(1))) unsigned int*)g,
        (__attribute__((address_space(3))) unsigned int*)l, 16, 0, 0);
}

// Software grid barrier. Precondition: all NBLK blocks co-resident.
// __syncthreads drains every wave's vmcnt; tid0's threadfences do the
// L2 writeback (release) / invalidate (acquire) a kernel boundary would.
__device__ __forceinline__ void grid_barrier(unsigned int* cnt, int tid) {
    __syncthreads();
    if (tid == 0) {
        __threadfence();                       // release: wb dirty L2
        atomicAdd(cnt, 1u);
        while (__hip_atomic_load(cnt, __ATOMIC_RELAXED,
                                 __HIP_MEMORY_SCOPE_AGENT) < NBLK) {
            __builtin_amdgcn_s_sleep(2);
        }
        __threadfence();                       // acquire: inv stale clean lines
    }
    __syncthreads();
}

// ---------------------------------------------------------------------------
// Fused prep: border-zero both volumes + weight conversions + zero barriers.
// ---------------------------------------------------------------------------
#define BORDER_ELEMS 1145088
__global__ __launch_bounds__(256) void prep_kernel(
    bf16* __restrict__ volA, bf16* __restrict__ volB,
    const float* __restrict__ s0, const float* __restrict__ s1,
    const float* __restrict__ s2, const float* __restrict__ s3,
    const float* __restrict__ sf,
    bf16* __restrict__ wb, bf16* __restrict__ wbf,
    unsigned int* __restrict__ cnt) {
    size_t tid = (size_t)blockIdx.x * 256 + threadIdx.x;

    if (tid < 4) cnt[tid] = 0u;

    if (tid < 4 * 27648) {                     // mid weights, contiguous dst
        int l = (int)(tid / 27648);
        int t = (int)(tid % 27648);
        const float* src = l == 0 ? s0 : l == 1 ? s1 : l == 2 ? s2 : s3;
        int tap = t >> 10, co = (t >> 5) & 31, ci = t & 31;
        wb[tid] = __float2bfloat16(src[(co * 32 + ci) * 27 + tap]);
    }
    if (tid < 27 * 16 * 32) {                  // final weights
        int tap = (int)(tid >> 9);
        int co  = ((int)tid >> 5) & 15;
        int ci  = (int)tid & 31;
        wbf[tid] = (co == 0) ? __float2bfloat16(sf[ci * 27 + tap])
                             : __float2bfloat16(0.f);
    }

    if (tid >= 2 * (size_t)BORDER_ELEMS) return;
    bf16* vol = (tid >= BORDER_ELEMS) ? volB : volA;
    size_t i = (tid >= BORDER_ELEMS) ? tid - BORDER_ELEMS : tid;
    size_t addr;
    if (i < 549120) {                       // d slices 0 and 49
        int dsl = (i < 274560) ? 0 : 49;
        size_t rem = i % 274560;
        addr = (size_t)dsl * PWp * ROW + rem;
    } else if (i < 751872) {                // w cols 0 and 129, d 1..48
        size_t j = i - 549120;
        int dd = (int)(j / 4224);
        int rr = (int)(j % 4224);
        int wcol = (rr < ROW) ? 0 : 129;
        int off = (rr < ROW) ? rr : rr - ROW;
        addr = ((size_t)(dd + 1) * PWp + wcol) * ROW + off;
    } else {                                // h rows 0 and 65, d 1..48, w 1..128
        size_t j = i - 751872;
        int dd = (int)(j >> 13);
        int rr = (int)(j & 8191);
        int w = rr >> 6;
        int e = rr & 63;
        int hrow = (e < 32) ? 0 : 65;
        addr = ((size_t)(dd + 1) * PWp + (w + 1)) * ROW + hrow * 32 + (e & 31);
    }
    vol[addr] = __float2bfloat16(0.f);
}

// ---------------------------------------------------------------------------
// Feature transpose (L and R fused via blockIdx.z):
// [256][64][128] f32 -> [64][128][256] f32
// ---------------------------------------------------------------------------
__global__ __launch_bounds__(256) void transpose_feat_kernel(
    const float* __restrict__ L, const float* __restrict__ R,
    float* __restrict__ Lt, float* __restrict__ Rt) {
    __shared__ float tile[32][257];
    const float* src = blockIdx.z ? R : L;
    float* dst       = blockIdx.z ? Rt : Lt;
    int tid = threadIdx.x;
    int w0  = blockIdx.x * 32;
    int h   = blockIdx.y;

#pragma unroll
    for (int it = 0; it < 32; ++it) {
        int c = it * 8 + (tid >> 5);
        tile[tid & 31][c] =
            src[(size_t)c * (HH * WW) + h * WW + w0 + (tid & 31)];
    }
    __syncthreads();

    int c_l = tid & 63, wg = tid >> 6;
#pragma unroll
    for (int it = 0; it < 8; ++it) {
        int w_i = it * 4 + wg;
        float* dp = dst + ((size_t)h * WW + w0 + w_i) * 256;
#pragma unroll
        for (int cc = 0; cc < 256; cc += 64)
            dp[cc + c_l] = tile[w_i][cc + c_l];
    }
}

// ---------------------------------------------------------------------------
// Cost volume from channels-last features -> padded [d][w][h][c] bf16
// ---------------------------------------------------------------------------
__global__ __launch_bounds__(256) void build_vol_kernel(
    const float* __restrict__ Lt, const float* __restrict__ Rt,
    bf16* __restrict__ vol) {
    int g  = threadIdx.x & 31;
    int wq = threadIdx.x >> 5;
    int w  = blockIdx.x * 8 + wq;
    int h  = blockIdx.y;

    const float4* lp = (const float4*)(Lt + ((size_t)h * WW + w) * 256 + g * 8);
    float4 l0 = lp[0], l1 = lp[1];
    const float* Rrow = Rt + (size_t)h * WW * 256;

    bf16* outp = vol + ((size_t)1 * PWp + (w + 1)) * ROW + (h + 1) * 32 + g;
    for (int d = 0; d < DD; ++d) {
        int x = w - d;
        float s = 0.f;
        if (x >= 0) {
            const float4* rp = (const float4*)(Rrow + (size_t)x * 256 + g * 8);
            float4 r0 = rp[0], r1 = rp[1];
            s = l0.x * r0.x + l0.y * r0.y + l0.z * r0.z + l0.w * r0.w +
                l1.x * r1.x + l1.y * r1.y + l1.z * r1.z + l1.w * r1.w;
            s *= 0.125f;
        }
        outp[(size_t)d * PWp * ROW] = __float2bfloat16(s);
    }
}

// ---------------------------------------------------------------------------
// ALL conv layers fused: 4x mid (32->32, lrelu) + final (32->1), persistent.
// Per-layer body is byte-identical to r10 (256 thr / 4 waves, grid 512 =
// (w-quad, d-segment of 3), 25 KB slices, 76 KB ring, dz-split async refill,
// swizzle involution on source + swizzled reads). Layers separated by
// grid_barrier instead of kernel boundaries.
// ---------------------------------------------------------------------------
__global__ __launch_bounds__(256, 2) void conv_all_kernel(
    bf16* __restrict__ volA, bf16* __restrict__ volB,
    const bf16* __restrict__ wb,
    const float* __restrict__ b0, const float* __restrict__ b1,
    const float* __restrict__ b2, const float* __restrict__ b3,
    const bf16* __restrict__ wbf, const float* __restrict__ bfin,
    float* __restrict__ out, unsigned int* __restrict__ cnt) {
    __shared__ bf16 lds[3 * SLICE_E];
    int id   = blockIdx.x;
    int xcd  = id & 7;
    int r    = id >> 3;                  // 0..63
    int wq   = r & 31;
    int dseg = xcd * 2 + (r >> 5);       // blocks sharing slices land on same XCD
    int w0   = wq * 4;
    int d0   = dseg * 3;
    int tid  = threadIdx.x;
    int wv   = tid >> 6;
    int lane = tid & 63;
    int arow = lane & 15;
    int kg   = lane >> 4;

    auto stage = [&](const bf16* X, int dslice, bf16* dst) {
#pragma unroll
        for (int row = 0; row < 6; ++row) {
            const bf16* base = X + ((size_t)dslice * PWp + (w0 + row)) * ROW;
            bf16* ldst = dst + row * ROW;
            int s = wv * 64 + lane;
            int gir = s ^ ((s >> 3) & 3);
            gload_lds16(base + gir * 8, ldst + wv * 512);
            if (tid < 8) {
                int s2 = 256 + lane;
                int gir2 = s2 ^ ((s2 >> 3) & 3);
                gload_lds16(base + gir2 * 8, ldst + 2048);
            }
        }
    };

    bf16* p0 = lds;
    bf16* p1 = lds + SLICE_E;
    bf16* p2 = lds + 2 * SLICE_E;

    // ---- 4 mid layers ----
    for (int l = 0; l < 4; ++l) {
        const bf16* Xl = (l & 1) ? volB : volA;
        bf16* Yl       = (l & 1) ? volA : volB;
        const short8* Wv = (const short8*)(wb + (size_t)l * 27648);
        const float* bp = (l == 0) ? b0 : (l == 1) ? b1 : (l == 2) ? b2 : b3;
        float bv0 = bp[arow];
        float bv1 = bp[arow + 16];

        stage(Xl, d0 + 0, p0);
        stage(Xl, d0 + 1, p1);
        stage(Xl, d0 + 2, p2);
        __syncthreads();

        for (int i = 0; i < 3; ++i) {
            f32x4 acc[4][2] = {};

            auto compute_dz = [&](const bf16* P, int dz) {
#pragma unroll
                for (int dx = 0; dx < 3; ++dx) {
                    const bf16* Ar = P + (wv + dx) * ROW;
#pragma unroll
                    for (int dy = 0; dy < 3; ++dy) {
                        int tap = dz * 9 + dy * 3 + dx;
                        short8 bb0 = Wv[tap * 128 + arow * 4 + kg];
                        short8 bb1 = Wv[tap * 128 + 64 + arow * 4 + kg];
                        int hh = arow + dy;
                        int s0 = (hh * 4 + kg) ^ ((hh >> 1) & 3);
#pragma unroll
                        for (int t = 0; t < 4; ++t) {
                            short8 a = *(const short8*)(Ar + s0 * 8 + t * 512);
                            acc[t][0] = __builtin_amdgcn_mfma_f32_16x16x32_bf16(
                                a, bb0, acc[t][0], 0, 0, 0);
                            acc[t][1] = __builtin_amdgcn_mfma_f32_16x16x32_bf16(
                                a, bb1, acc[t][1], 0, 0, 0);
                        }
                    }
                }
            };

            compute_dz(p0, 0);
            __syncthreads();                       // all waves done with p0
            if (i < 2) stage(Xl, d0 + i + 3, p0);  // async refill
            compute_dz(p1, 1);
            compute_dz(p2, 2);

            int d = d0 + i;
            bf16* Yp = Yl + (((size_t)(d + 1) * PWp + (w0 + wv + 1))) * ROW + 32;
#pragma unroll
            for (int t = 0; t < 4; ++t)
#pragma unroll
                for (int rr = 0; rr < 4; ++rr) {
                    int o = t * 16 + kg * 4 + rr;
                    float v0 = acc[t][0][rr] + bv0;
                    float v1 = acc[t][1][rr] + bv1;
                    v0 = fmaxf(v0, 0.f) + 0.2f * fminf(v0, 0.f);
                    v1 = fmaxf(v1, 0.f) + 0.2f * fminf(v1, 0.f);
                    Yp[o * 32 + arow]      = __float2bfloat16(v0);
                    Yp[o * 32 + arow + 16] = __float2bfloat16(v1);
                }
            __syncthreads();                       // refill landed
            bf16* tswap = p0; p0 = p1; p1 = p2; p2 = tswap;
        }

        grid_barrier(cnt + l, tid);                // layer boundary
    }

    // ---- final layer: volA -> out ----
    {
        const bf16* Xl = volA;
        float bv = bfin[0];
        const short8* Wv = (const short8*)wbf;

        stage(Xl, d0 + 0, p0);
        stage(Xl, d0 + 1, p1);
        stage(Xl, d0 + 2, p2);
        __syncthreads();

        for (int i = 0; i < 3; ++i) {
            f32x4 acc[4] = {};

            auto compute_dz = [&](const bf16* P, int dz) {
#pragma unroll
                for (int dx = 0; dx < 3; ++dx) {
                    const bf16* Ar = P + (wv + dx) * ROW;
#pragma unroll
                    for (int dy = 0; dy < 3; ++dy) {
                        int tap = dz * 9 + dy * 3 + dx;
                        short8 b = Wv[tap * 64 + arow * 4 + kg];
                        int hh = arow + dy;
                        int s0 = (hh * 4 + kg) ^ ((hh >> 1) & 3);
#pragma unroll
                        for (int t = 0; t < 4; ++t) {
                            short8 a = *(const short8*)(Ar + s0 * 8 + t * 512);
                            acc[t] = __builtin_amdgcn_mfma_f32_16x16x32_bf16(
                                a, b, acc[t], 0, 0, 0);
                        }
                    }
                }
            };

            compute_dz(p0, 0);
            __syncthreads();
            if (i < 2) stage(Xl, d0 + i + 3, p0);
            compute_dz(p1, 1);
            compute_dz(p2, 2);

            if (arow == 0) {
                int d = d0 + i;
#pragma unroll
                for (int t = 0; t < 4; ++t)
#pragma unroll
                    for (int rr = 0; rr < 4; ++rr) {
                        int o = t * 16 + kg * 4 + rr;
                        out[((size_t)d * HH + o) * WW + (w0 + wv)] =
                            acc[t][rr] + bv;
                    }
            }
            __syncthreads();
            bf16* tswap = p0; p0 = p1; p1 = p2; p2 = tswap;
        }
    }
}

// ---------------------------------------------------------------------------
// Launch
// ---------------------------------------------------------------------------
extern "C" void kernel_launch(void* const* d_in, const int* in_sizes, int n_in,
                              void* d_out, int out_size, void* d_ws, size_t ws_size,
                              hipStream_t stream) {
    const float* left  = (const float*)d_in[0];
    const float* right = (const float*)d_in[1];
    const float* w0 = (const float*)d_in[2];
    const float* b0 = (const float*)d_in[3];
    const float* w1 = (const float*)d_in[4];
    const float* b1 = (const float*)d_in[5];
    const float* w2 = (const float*)d_in[6];
    const float* b2 = (const float*)d_in[7];
    const float* w3 = (const float*)d_in[8];
    const float* b3 = (const float*)d_in[9];
    const float* wf = (const float*)d_in[10];
    const float* bf = (const float*)d_in[11];

    bf16* volA = (bf16*)d_ws;
    bf16* volB = volA + PVOL;
    bf16* wb0  = volB + PVOL;                 // 4 x 27648 contiguous
    bf16* wbf  = wb0 + 4 * 27648;             // 13824 elems
    float* Lt  = (float*)(wbf + 13824 + 32);  // 16B-aligned
    float* Rt  = Lt + FEAT;
    unsigned int* cnt = (unsigned int*)(Rt + FEAT);  // 4 barrier counters

    prep_kernel<<<(2 * BORDER_ELEMS + 255) / 256, 256, 0, stream>>>(
        volA, volB, w0, w1, w2, w3, wf, wb0, wbf, cnt);

    transpose_feat_kernel<<<dim3(WW / 32, HH, 2), 256, 0, stream>>>(left, right, Lt, Rt);

    build_vol_kernel<<<dim3(WW / 8, HH), 256, 0, stream>>>(Lt, Rt, volA);

    conv_all_kernel<<<NBLK, 256, 0, stream>>>(
        volA, volB, wb0, b0, b1, b2, b3, wbf, bf, (float*)d_out, cnt);
}

// Round 12
// 201.983 us; speedup vs baseline: 2.5586x; 2.5586x over previous
//
#include <hip/hip_runtime.h>
#include <hip/hip_bf16.h>

// Problem constants
#define HH 64
#define WW 128
#define DD 48
#define CG 8
// Padded volume layout: [d 50][w 130][h 66][c 32]  (channels-last, h inner)
#define PD 50
#define PWp 130
#define PHp 66
#define ROW 2112                               // elems per (d,w) row = 66*32
#define PVOL ((size_t)PD * PWp * ROW)          // 13,728,000 elems
#define FEAT ((size_t)HH * WW * 256)
#define SLICE_E (6 * ROW)                      // 12672 elems = 25344 B

typedef __hip_bfloat16 bf16;
typedef __attribute__((ext_vector_type(8))) short short8;
typedef __attribute__((ext_vector_type(4))) short short4v;
typedef __attribute__((ext_vector_type(4))) float f32x4;

__device__ __forceinline__ void gload_lds16(const bf16* g, bf16* l) {
    __builtin_amdgcn_global_load_lds(
        (const __attribute__((address_space(1))) unsigned int*)g,
        (__attribute__((address_space(3))) unsigned int*)l, 16, 0, 0);
}

// ---------------------------------------------------------------------------
// Fused prep: border-zero both volumes + all weight conversions.
// ---------------------------------------------------------------------------
#define BORDER_ELEMS 1145088
__global__ __launch_bounds__(256) void prep_kernel(
    bf16* __restrict__ volA, bf16* __restrict__ volB,
    const float* __restrict__ s0, const float* __restrict__ s1,
    const float* __restrict__ s2, const float* __restrict__ s3,
    const float* __restrict__ sf,
    bf16* __restrict__ wb, bf16* __restrict__ wbf) {
    size_t tid = (size_t)blockIdx.x * 256 + threadIdx.x;

    if (tid < 4 * 27648) {                     // mid weights [l][tap][co][ci]
        int l = (int)(tid / 27648);
        int t = (int)(tid % 27648);
        const float* src = l == 0 ? s0 : l == 1 ? s1 : l == 2 ? s2 : s3;
        int tap = t >> 10, co = (t >> 5) & 31, ci = t & 31;
        wb[tid] = __float2bfloat16(src[(co * 32 + ci) * 27 + tap]);
    }
    if (tid < 27 * 16 * 32) {                  // final weights [tap][co<16][ci]
        int tap = (int)(tid >> 9);
        int co  = ((int)tid >> 5) & 15;
        int ci  = (int)tid & 31;
        wbf[tid] = (co == 0) ? __float2bfloat16(sf[ci * 27 + tap])
                             : __float2bfloat16(0.f);
    }

    if (tid >= 2 * (size_t)BORDER_ELEMS) return;
    bf16* vol = (tid >= BORDER_ELEMS) ? volB : volA;
    size_t i = (tid >= BORDER_ELEMS) ? tid - BORDER_ELEMS : tid;
    size_t addr;
    if (i < 549120) {                       // d slices 0 and 49
        int dsl = (i < 274560) ? 0 : 49;
        size_t rem = i % 274560;
        addr = (size_t)dsl * PWp * ROW + rem;
    } else if (i < 751872) {                // w cols 0 and 129, d 1..48
        size_t j = i - 549120;
        int dd = (int)(j / 4224);
        int rr = (int)(j % 4224);
        int wcol = (rr < ROW) ? 0 : 129;
        int off = (rr < ROW) ? rr : rr - ROW;
        addr = ((size_t)(dd + 1) * PWp + wcol) * ROW + off;
    } else {                                // h rows 0 and 65, d 1..48, w 1..128
        size_t j = i - 751872;
        int dd = (int)(j >> 13);
        int rr = (int)(j & 8191);
        int w = rr >> 6;
        int e = rr & 63;
        int hrow = (e < 32) ? 0 : 65;
        addr = ((size_t)(dd + 1) * PWp + (w + 1)) * ROW + hrow * 32 + (e & 31);
    }
    vol[addr] = __float2bfloat16(0.f);
}

// ---------------------------------------------------------------------------
// Feature transpose (L and R fused via blockIdx.z):
// [256][64][128] f32 -> [64][128][256] f32
// ---------------------------------------------------------------------------
__global__ __launch_bounds__(256) void transpose_feat_kernel(
    const float* __restrict__ L, const float* __restrict__ R,
    float* __restrict__ Lt, float* __restrict__ Rt) {
    __shared__ float tile[32][257];
    const float* src = blockIdx.z ? R : L;
    float* dst       = blockIdx.z ? Rt : Lt;
    int tid = threadIdx.x;
    int w0  = blockIdx.x * 32;
    int h   = blockIdx.y;

#pragma unroll
    for (int it = 0; it < 32; ++it) {
        int c = it * 8 + (tid >> 5);
        tile[tid & 31][c] =
            src[(size_t)c * (HH * WW) + h * WW + w0 + (tid & 31)];
    }
    __syncthreads();

    int c_l = tid & 63, wg = tid >> 6;
#pragma unroll
    for (int it = 0; it < 8; ++it) {
        int w_i = it * 4 + wg;
        float* dp = dst + ((size_t)h * WW + w0 + w_i) * 256;
#pragma unroll
        for (int cc = 0; cc < 256; cc += 64)
            dp[cc + c_l] = tile[w_i][cc + c_l];
    }
}

// ---------------------------------------------------------------------------
// Cost volume from channels-last features -> padded [d][w][h][c] bf16
// ---------------------------------------------------------------------------
__global__ __launch_bounds__(256) void build_vol_kernel(
    const float* __restrict__ Lt, const float* __restrict__ Rt,
    bf16* __restrict__ vol) {
    int g  = threadIdx.x & 31;
    int wq = threadIdx.x >> 5;
    int w  = blockIdx.x * 8 + wq;
    int h  = blockIdx.y;

    const float4* lp = (const float4*)(Lt + ((size_t)h * WW + w) * 256 + g * 8);
    float4 l0 = lp[0], l1 = lp[1];
    const float* Rrow = Rt + (size_t)h * WW * 256;

    bf16* outp = vol + ((size_t)1 * PWp + (w + 1)) * ROW + (h + 1) * 32 + g;
    for (int d = 0; d < DD; ++d) {
        int x = w - d;
        float s = 0.f;
        if (x >= 0) {
            const float4* rp = (const float4*)(Rrow + (size_t)x * 256 + g * 8);
            float4 r0 = rp[0], r1 = rp[1];
            s = l0.x * r0.x + l0.y * r0.y + l0.z * r0.z + l0.w * r0.w +
                l1.x * r1.x + l1.y * r1.y + l1.z * r1.z + l1.w * r1.w;
            s *= 0.125f;
        }
        outp[(size_t)d * PWp * ROW] = __float2bfloat16(s);
    }
}

// ---------------------------------------------------------------------------
// Mid conv, pipelined d-walk (r10 structure EXACTLY: 256 thr / 4 waves,
// grid 512 = (w-quad, d-segment of 3), 25 KB slices, 76 KB ring, 2 blk/CU,
// dz-split async refill). NEW r12: MFMA operand swap mfma(b, a, acc) --
// D rows become channels, cols spatial -- so each thread holds 4 CONSECUTIVE
// channels at one spatial point: epilogue = 8x 8B short4 stores (was 32x 2B).
// Fragment addressing unchanged (A/B lane maps are identical, r2-verified).
// Swizzle involution f(s)=s^((s>>3)&3) on source; reads slot=(hh*4+kg)^((hh>>1)&3).
// ---------------------------------------------------------------------------
__global__ __launch_bounds__(256, 2) void conv_mid_kernel(
    const bf16* __restrict__ X, const bf16* __restrict__ Wb,
    const float* __restrict__ bias, bf16* __restrict__ Y) {
    __shared__ bf16 lds[3 * SLICE_E];
    int id   = blockIdx.x;
    int xcd  = id & 7;
    int r    = id >> 3;                  // 0..63
    int wq   = r & 31;
    int dseg = xcd * 2 + (r >> 5);       // blocks sharing slices land on same XCD
    int w0   = wq * 4;
    int d0   = dseg * 3;
    int tid  = threadIdx.x;
    int wv   = tid >> 6;
    int lane = tid & 63;
    int arow = lane & 15;
    int kg   = lane >> 4;

    auto stage = [&](int dslice, bf16* dst) {
#pragma unroll
        for (int row = 0; row < 6; ++row) {
            const bf16* base = X + ((size_t)dslice * PWp + (w0 + row)) * ROW;
            bf16* ldst = dst + row * ROW;
            int s = wv * 64 + lane;
            int gir = s ^ ((s >> 3) & 3);
            gload_lds16(base + gir * 8, ldst + wv * 512);
            if (tid < 8) {
                int s2 = 256 + lane;
                int gir2 = s2 ^ ((s2 >> 3) & 3);
                gload_lds16(base + gir2 * 8, ldst + 2048);
            }
        }
    };

    bf16* p0 = lds;
    bf16* p1 = lds + SLICE_E;
    bf16* p2 = lds + 2 * SLICE_E;
    stage(d0 + 0, p0);
    stage(d0 + 1, p1);
    stage(d0 + 2, p2);
    __syncthreads();

    const short8* Wv = (const short8*)Wb;
    float4 bva = *(const float4*)(bias + kg * 4);        // channels kg*4..+3
    float4 bvb = *(const float4*)(bias + 16 + kg * 4);   // channels 16+kg*4..+3

    for (int i = 0; i < 3; ++i) {
        f32x4 acc[4][2] = {};

        // accumulate one dz-slice worth of taps from ring slot P
        auto compute_dz = [&](const bf16* P, int dz) {
#pragma unroll
            for (int dx = 0; dx < 3; ++dx) {
                const bf16* Ar = P + (wv + dx) * ROW;
#pragma unroll
                for (int dy = 0; dy < 3; ++dy) {
                    int tap = dz * 9 + dy * 3 + dx;
                    short8 b0 = Wv[tap * 128 + arow * 4 + kg];
                    short8 b1 = Wv[tap * 128 + 64 + arow * 4 + kg];
                    int hh = arow + dy;
                    int s0 = (hh * 4 + kg) ^ ((hh >> 1) & 3);
#pragma unroll
                    for (int t = 0; t < 4; ++t) {
                        short8 a = *(const short8*)(Ar + s0 * 8 + t * 512);
                        // swapped: weights as M (rows), activations as N (cols)
                        acc[t][0] = __builtin_amdgcn_mfma_f32_16x16x32_bf16(
                            b0, a, acc[t][0], 0, 0, 0);
                        acc[t][1] = __builtin_amdgcn_mfma_f32_16x16x32_bf16(
                            b1, a, acc[t][1], 0, 0, 0);
                    }
                }
            }
        };

        // Phase A: dz=0 -- sole reader of p0
        compute_dz(p0, 0);
        __syncthreads();                       // all waves done with p0
        if (i < 2) stage(d0 + i + 3, p0);      // async refill into freed slot
        // Phase B: dz=1,2 -- stage latency hides under this
        compute_dz(p1, 1);
        compute_dz(p2, 2);

        int d = d0 + i;
        // D mapping (swapped): col=arow -> spatial h (within tile t),
        // row=kg*4+rr -> channel. Thread stores 4 consecutive channels = 8B.
        bf16* Yp = Y + (((size_t)(d + 1) * PWp + (w0 + wv + 1))) * ROW + 32;
#pragma unroll
        for (int t = 0; t < 4; ++t) {
            int hbase = (t * 16 + arow) * 32;
#pragma unroll
            for (int tc = 0; tc < 2; ++tc) {
                float4 bb = tc ? bvb : bva;
                float v0 = acc[t][tc][0] + bb.x;
                float v1 = acc[t][tc][1] + bb.y;
                float v2 = acc[t][tc][2] + bb.z;
                float v3 = acc[t][tc][3] + bb.w;
                v0 = fmaxf(v0, 0.f) + 0.2f * fminf(v0, 0.f);
                v1 = fmaxf(v1, 0.f) + 0.2f * fminf(v1, 0.f);
                v2 = fmaxf(v2, 0.f) + 0.2f * fminf(v2, 0.f);
                v3 = fmaxf(v3, 0.f) + 0.2f * fminf(v3, 0.f);
                union { short4v s4; bf16 b[4]; } u;
                u.b[0] = __float2bfloat16(v0);
                u.b[1] = __float2bfloat16(v1);
                u.b[2] = __float2bfloat16(v2);
                u.b[3] = __float2bfloat16(v3);
                *(short4v*)(Yp + hbase + tc * 16 + kg * 4) = u.s4;
            }
        }
        __syncthreads();                       // refill landed
        bf16* tswap = p0; p0 = p1; p1 = p2; p2 = tswap;
    }
}

// ---------------------------------------------------------------------------
// Final conv (32ch -> 1), r10 structure unchanged. fp32 out [d][h][w].
// ---------------------------------------------------------------------------
__global__ __launch_bounds__(256, 2) void conv_final_kernel(
    const bf16* __restrict__ X, const bf16* __restrict__ Wb,
    const float* __restrict__ bias, float* __restrict__ out) {
    __shared__ bf16 lds[3 * SLICE_E];
    int id   = blockIdx.x;
    int xcd  = id & 7;
    int r    = id >> 3;
    int wq   = r & 31;
    int dseg = xcd * 2 + (r >> 5);
    int w0   = wq * 4;
    int d0   = dseg * 3;
    int tid  = threadIdx.x;
    int wv   = tid >> 6;
    int lane = tid & 63;
    int arow = lane & 15;
    int kg   = lane >> 4;

    auto stage = [&](int dslice, bf16* dst) {
#pragma unroll
        for (int row = 0; row < 6; ++row) {
            const bf16* base = X + ((size_t)dslice * PWp + (w0 + row)) * ROW;
            bf16* ldst = dst + row * ROW;
            int s = wv * 64 + lane;
            int gir = s ^ ((s >> 3) & 3);
            gload_lds16(base + gir * 8, ldst + wv * 512);
            if (tid < 8) {
                int s2 = 256 + lane;
                int gir2 = s2 ^ ((s2 >> 3) & 3);
                gload_lds16(base + gir2 * 8, ldst + 2048);
            }
        }
    };

    bf16* p0 = lds;
    bf16* p1 = lds + SLICE_E;
    bf16* p2 = lds + 2 * SLICE_E;
    stage(d0 + 0, p0);
    stage(d0 + 1, p1);
    stage(d0 + 2, p2);
    __syncthreads();

    const short8* Wv = (const short8*)Wb;
    float bv = bias[0];

    for (int i = 0; i < 3; ++i) {
        f32x4 acc[4] = {};

        auto compute_dz = [&](const bf16* P, int dz) {
#pragma unroll
            for (int dx = 0; dx < 3; ++dx) {
                const bf16* Ar = P + (wv + dx) * ROW;
#pragma unroll
                for (int dy = 0; dy < 3; ++dy) {
                    int tap = dz * 9 + dy * 3 + dx;
                    short8 b = Wv[tap * 64 + arow * 4 + kg];
                    int hh = arow + dy;
                    int s0 = (hh * 4 + kg) ^ ((hh >> 1) & 3);
#pragma unroll
                    for (int t = 0; t < 4; ++t) {
                        short8 a = *(const short8*)(Ar + s0 * 8 + t * 512);
                        acc[t] = __builtin_amdgcn_mfma_f32_16x16x32_bf16(
                            a, b, acc[t], 0, 0, 0);
                    }
                }
            }
        };

        compute_dz(p0, 0);
        __syncthreads();
        if (i < 2) stage(d0 + i + 3, p0);
        compute_dz(p1, 1);
        compute_dz(p2, 2);

        if (arow == 0) {
            int d = d0 + i;
#pragma unroll
            for (int t = 0; t < 4; ++t)
#pragma unroll
                for (int rr = 0; rr < 4; ++rr) {
                    int o = t * 16 + kg * 4 + rr;
                    out[((size_t)d * HH + o) * WW + (w0 + wv)] = acc[t][rr] + bv;
                }
        }
        __syncthreads();
        bf16* tswap = p0; p0 = p1; p1 = p2; p2 = tswap;
    }
}

// ---------------------------------------------------------------------------
// Launch
// ---------------------------------------------------------------------------
extern "C" void kernel_launch(void* const* d_in, const int* in_sizes, int n_in,
                              void* d_out, int out_size, void* d_ws, size_t ws_size,
                              hipStream_t stream) {
    const float* left  = (const float*)d_in[0];
    const float* right = (const float*)d_in[1];
    const float* w0 = (const float*)d_in[2];
    const float* b0 = (const float*)d_in[3];
    const float* w1 = (const float*)d_in[4];
    const float* b1 = (const float*)d_in[5];
    const float* w2 = (const float*)d_in[6];
    const float* b2 = (const float*)d_in[7];
    const float* w3 = (const float*)d_in[8];
    const float* b3 = (const float*)d_in[9];
    const float* wf = (const float*)d_in[10];
    const float* bf = (const float*)d_in[11];

    bf16* volA = (bf16*)d_ws;
    bf16* volB = volA + PVOL;
    bf16* wb0  = volB + PVOL;                 // 4 x 27648 contiguous
    bf16* wbf  = wb0 + 4 * 27648;             // 13824 elems
    float* Lt  = (float*)(wbf + 13824 + 32);  // 16B-aligned
    float* Rt  = Lt + FEAT;

    prep_kernel<<<(2 * BORDER_ELEMS + 255) / 256, 256, 0, stream>>>(
        volA, volB, w0, w1, w2, w3, wf, wb0, wbf);

    transpose_feat_kernel<<<dim3(WW / 32, HH, 2), 256, 0, stream>>>(left, right, Lt, Rt);

    build_vol_kernel<<<dim3(WW / 8, HH), 256, 0, stream>>>(Lt, Rt, volA);

    int grid = 512;   // 32 w-quads x 16 d-segments, all-resident (2 blocks/CU)
    conv_mid_kernel<<<grid, 256, 0, stream>>>(volA, wb0 + 0 * 27648, b0, volB);
    conv_mid_kernel<<<grid, 256, 0, stream>>>(volB, wb0 + 1 * 27648, b1, volA);
    conv_mid_kernel<<<grid, 256, 0, stream>>>(volA, wb0 + 2 * 27648, b2, volB);
    conv_mid_kernel<<<grid, 256, 0, stream>>>(volB, wb0 + 3 * 27648, b3, volA);
    conv_final_kernel<<<grid, 256, 0, stream>>>(volA, wbf, bf, (float*)d_out);
}

// Round 13
// 189.552 us; speedup vs baseline: 2.7264x; 1.0656x over previous
//
#include <hip/hip_runtime.h>
#include <hip/hip_bf16.h>

// Problem constants
#define HH 64
#define WW 128
#define DD 48
#define CG 8
// Padded volume layout: [d 50][w 130][h 66][c 32]  (channels-last, h inner)
#define PD 50
#define PWp 130
#define PHp 66
#define ROW 2112                               // elems per (d,w) row = 66*32
#define PVOL ((size_t)PD * PWp * ROW)          // 13,728,000 elems
#define FEAT ((size_t)HH * WW * 256)
#define SLICE_E (6 * ROW)                      // 12672 elems = 25344 B

typedef __hip_bfloat16 bf16;
typedef __attribute__((ext_vector_type(8))) short short8;
typedef __attribute__((ext_vector_type(4))) float f32x4;

__device__ __forceinline__ void gload_lds16(const bf16* g, bf16* l) {
    __builtin_amdgcn_global_load_lds(
        (const __attribute__((address_space(1))) unsigned int*)g,
        (__attribute__((address_space(3))) unsigned int*)l, 16, 0, 0);
}

// ---------------------------------------------------------------------------
// Border zeroing of both padded volumes
// ---------------------------------------------------------------------------
#define BORDER_ELEMS 1145088
__global__ __launch_bounds__(256) void border_zero_kernel(bf16* __restrict__ volA,
                                                          bf16* __restrict__ volB) {
    size_t tid = (size_t)blockIdx.x * 256 + threadIdx.x;
    if (tid >= 2 * (size_t)BORDER_ELEMS) return;
    bf16* vol = (tid >= BORDER_ELEMS) ? volB : volA;
    size_t i = (tid >= BORDER_ELEMS) ? tid - BORDER_ELEMS : tid;
    size_t addr;
    if (i < 549120) {                       // d slices 0 and 49
        int dsl = (i < 274560) ? 0 : 49;
        size_t rem = i % 274560;
        addr = (size_t)dsl * PWp * ROW + rem;
    } else if (i < 751872) {                // w cols 0 and 129, d 1..48
        size_t j = i - 549120;
        int dd = (int)(j / 4224);
        int rr = (int)(j % 4224);
        int wcol = (rr < ROW) ? 0 : 129;
        int off = (rr < ROW) ? rr : rr - ROW;
        addr = ((size_t)(dd + 1) * PWp + wcol) * ROW + off;
    } else {                                // h rows 0 and 65, d 1..48, w 1..128
        size_t j = i - 751872;
        int dd = (int)(j >> 13);
        int rr = (int)(j & 8191);
        int w = rr >> 6;
        int e = rr & 63;
        int hrow = (e < 32) ? 0 : 65;
        addr = ((size_t)(dd + 1) * PWp + (w + 1)) * ROW + hrow * 32 + (e & 31);
    }
    vol[addr] = __float2bfloat16(0.f);
}

// ---------------------------------------------------------------------------
// Feature transpose (L and R fused via blockIdx.z):
// [256][64][128] f32 -> [64][128][256] f32
// ---------------------------------------------------------------------------
__global__ __launch_bounds__(256) void transpose_feat_kernel(
    const float* __restrict__ L, const float* __restrict__ R,
    float* __restrict__ Lt, float* __restrict__ Rt) {
    __shared__ float tile[32][257];
    const float* src = blockIdx.z ? R : L;
    float* dst       = blockIdx.z ? Rt : Lt;
    int tid = threadIdx.x;
    int w0  = blockIdx.x * 32;
    int h   = blockIdx.y;

#pragma unroll
    for (int it = 0; it < 32; ++it) {
        int c = it * 8 + (tid >> 5);
        tile[tid & 31][c] =
            src[(size_t)c * (HH * WW) + h * WW + w0 + (tid & 31)];
    }
    __syncthreads();

    int c_l = tid & 63, wg = tid >> 6;
#pragma unroll
    for (int it = 0; it < 8; ++it) {
        int w_i = it * 4 + wg;
        float* dp = dst + ((size_t)h * WW + w0 + w_i) * 256;
#pragma unroll
        for (int cc = 0; cc < 256; cc += 64)
            dp[cc + c_l] = tile[w_i][cc + c_l];
    }
}

// ---------------------------------------------------------------------------
// Weight conversion (4 mid layers fused): fp32 [32][32][27] -> bf16 [tap][co][ci]
// ---------------------------------------------------------------------------
__global__ void convert_w_mid4_kernel(const float* __restrict__ s0,
                                      const float* __restrict__ s1,
                                      const float* __restrict__ s2,
                                      const float* __restrict__ s3,
                                      bf16* __restrict__ d0, bf16* __restrict__ d1,
                                      bf16* __restrict__ d2, bf16* __restrict__ d3) {
    int tid = blockIdx.x * 256 + threadIdx.x;
    if (tid >= 4 * 27648) return;
    int layer = tid / 27648;
    int t = tid % 27648;
    const float* src = layer == 0 ? s0 : layer == 1 ? s1 : layer == 2 ? s2 : s3;
    bf16* dst = layer == 0 ? d0 : layer == 1 ? d1 : layer == 2 ? d2 : d3;
    int tap = t >> 10, co = (t >> 5) & 31, ci = t & 31;
    dst[t] = __float2bfloat16(src[(co * 32 + ci) * 27 + tap]);
}

__global__ void convert_w_final_kernel(const float* __restrict__ src,
                                       bf16* __restrict__ dst) {
    int tid = blockIdx.x * 256 + threadIdx.x;
    if (tid >= 27 * 16 * 32) return;
    int tap = tid >> 9;
    int co  = (tid >> 5) & 15;
    int ci  = tid & 31;
    dst[tid] = (co == 0) ? __float2bfloat16(src[ci * 27 + tap])
                         : __float2bfloat16(0.f);
}

// ---------------------------------------------------------------------------
// Cost volume from channels-last features -> padded [d][w][h][c] bf16
// ---------------------------------------------------------------------------
__global__ __launch_bounds__(256) void build_vol_kernel(
    const float* __restrict__ Lt, const float* __restrict__ Rt,
    bf16* __restrict__ vol) {
    int g  = threadIdx.x & 31;
    int wq = threadIdx.x >> 5;
    int w  = blockIdx.x * 8 + wq;
    int h  = blockIdx.y;

    const float4* lp = (const float4*)(Lt + ((size_t)h * WW + w) * 256 + g * 8);
    float4 l0 = lp[0], l1 = lp[1];
    const float* Rrow = Rt + (size_t)h * WW * 256;

    bf16* outp = vol + ((size_t)1 * PWp + (w + 1)) * ROW + (h + 1) * 32 + g;
    for (int d = 0; d < DD; ++d) {
        int x = w - d;
        float s = 0.f;
        if (x >= 0) {
            const float4* rp = (const float4*)(Rrow + (size_t)x * 256 + g * 8);
            float4 r0 = rp[0], r1 = rp[1];
            s = l0.x * r0.x + l0.y * r0.y + l0.z * r0.z + l0.w * r0.w +
                l1.x * r1.x + l1.y * r1.y + l1.z * r1.z + l1.w * r1.w;
            s *= 0.125f;
        }
        outp[(size_t)d * PWp * ROW] = __float2bfloat16(s);
    }
}

// ---------------------------------------------------------------------------
// Mid conv, pipelined d-walk (EXACT r6 block/grid/LDS/stage structure:
// 256 thr / 4 waves, grid 512 = (w-quad, d-segment of 3), full-h 25 KB
// slices, 76 KB ring, 2 blocks/CU). Wave = one w column, M=64 x N=32.
// dz-split async refill: compute dz=0 (only reader of ring slot p0),
// barrier, ISSUE refill into p0, then compute dz=1,2 + epilogue before
// the end barrier drains vmcnt.
// Swizzle involution f(s)=s^((s>>3)&3) on global source; reads use
// slot=(hh*4+kg)^((hh>>1)&3). Verified r5/r6: 0 bank conflicts.
// ---------------------------------------------------------------------------
__global__ __launch_bounds__(256, 2) void conv_mid_kernel(
    const bf16* __restrict__ X, const bf16* __restrict__ Wb,
    const float* __restrict__ bias, bf16* __restrict__ Y) {
    __shared__ bf16 lds[3 * SLICE_E];
    int id   = blockIdx.x;
    int xcd  = id & 7;
    int r    = id >> 3;                  // 0..63
    int wq   = r & 31;
    int dseg = xcd * 2 + (r >> 5);       // blocks sharing slices land on same XCD
    int w0   = wq * 4;
    int d0   = dseg * 3;
    int tid  = threadIdx.x;
    int wv   = tid >> 6;
    int lane = tid & 63;
    int arow = lane & 15;
    int kg   = lane >> 4;

    auto stage = [&](int dslice, bf16* dst) {
#pragma unroll
        for (int row = 0; row < 6; ++row) {
            const bf16* base = X + ((size_t)dslice * PWp + (w0 + row)) * ROW;
            bf16* ldst = dst + row * ROW;
            int s = wv * 64 + lane;
            int gir = s ^ ((s >> 3) & 3);
            gload_lds16(base + gir * 8, ldst + wv * 512);
            if (tid < 8) {
                int s2 = 256 + lane;
                int gir2 = s2 ^ ((s2 >> 3) & 3);
                gload_lds16(base + gir2 * 8, ldst + 2048);
            }
        }
    };

    bf16* p0 = lds;
    bf16* p1 = lds + SLICE_E;
    bf16* p2 = lds + 2 * SLICE_E;
    stage(d0 + 0, p0);
    stage(d0 + 1, p1);
    stage(d0 + 2, p2);
    __syncthreads();

    const short8* Wv = (const short8*)Wb;
    float bv0 = bias[arow];
    float bv1 = bias[arow + 16];

    for (int i = 0; i < 3; ++i) {
        f32x4 acc[4][2] = {};

        // accumulate one dz-slice worth of taps from ring slot P
        auto compute_dz = [&](const bf16* P, int dz) {
#pragma unroll
            for (int dx = 0; dx < 3; ++dx) {
                const bf16* Ar = P + (wv + dx) * ROW;
#pragma unroll
                for (int dy = 0; dy < 3; ++dy) {
                    int tap = dz * 9 + dy * 3 + dx;
                    short8 b0 = Wv[tap * 128 + arow * 4 + kg];
                    short8 b1 = Wv[tap * 128 + 64 + arow * 4 + kg];
                    int hh = arow + dy;
                    int s0 = (hh * 4 + kg) ^ ((hh >> 1) & 3);
#pragma unroll
                    for (int t = 0; t < 4; ++t) {
                        short8 a = *(const short8*)(Ar + s0 * 8 + t * 512);
                        acc[t][0] = __builtin_amdgcn_mfma_f32_16x16x32_bf16(
                            a, b0, acc[t][0], 0, 0, 0);
                        acc[t][1] = __builtin_amdgcn_mfma_f32_16x16x32_bf16(
                            a, b1, acc[t][1], 0, 0, 0);
                    }
                }
            }
        };

        // Phase A: dz=0 -- sole reader of p0
        compute_dz(p0, 0);
        __syncthreads();                       // all waves done with p0
        if (i < 2) stage(d0 + i + 3, p0);      // async refill into freed slot
        // Phase B: dz=1,2 -- stage latency hides under this
        compute_dz(p1, 1);
        compute_dz(p2, 2);

        int d = d0 + i;
        bf16* Yp = Y + (((size_t)(d + 1) * PWp + (w0 + wv + 1))) * ROW + 32;
#pragma unroll
        for (int t = 0; t < 4; ++t)
#pragma unroll
            for (int rr = 0; rr < 4; ++rr) {
                int o = t * 16 + kg * 4 + rr;
                float v0 = acc[t][0][rr] + bv0;
                float v1 = acc[t][1][rr] + bv1;
                v0 = fmaxf(v0, 0.f) + 0.2f * fminf(v0, 0.f);
                v1 = fmaxf(v1, 0.f) + 0.2f * fminf(v1, 0.f);
                Yp[o * 32 + arow]      = __float2bfloat16(v0);
                Yp[o * 32 + arow + 16] = __float2bfloat16(v1);
            }
        __syncthreads();                       // vmcnt(0) drained here: slice landed
        bf16* tswap = p0; p0 = p1; p1 = p2; p2 = tswap;
    }
}

// ---------------------------------------------------------------------------
// Final conv (32ch -> 1), same structure + dz-split async refill. fp32 out.
// ---------------------------------------------------------------------------
__global__ __launch_bounds__(256, 2) void conv_final_kernel(
    const bf16* __restrict__ X, const bf16* __restrict__ Wb,
    const float* __restrict__ bias, float* __restrict__ out) {
    __shared__ bf16 lds[3 * SLICE_E];
    int id   = blockIdx.x;
    int xcd  = id & 7;
    int r    = id >> 3;
    int wq   = r & 31;
    int dseg = xcd * 2 + (r >> 5);
    int w0   = wq * 4;
    int d0   = dseg * 3;
    int tid  = threadIdx.x;
    int wv   = tid >> 6;
    int lane = tid & 63;
    int arow = lane & 15;
    int kg   = lane >> 4;

    auto stage = [&](int dslice, bf16* dst) {
#pragma unroll
        for (int row = 0; row < 6; ++row) {
            const bf16* base = X + ((size_t)dslice * PWp + (w0 + row)) * ROW;
            bf16* ldst = dst + row * ROW;
            int s = wv * 64 + lane;
            int gir = s ^ ((s >> 3) & 3);
            gload_lds16(base + gir * 8, ldst + wv * 512);
            if (tid < 8) {
                int s2 = 256 + lane;
                int gir2 = s2 ^ ((s2 >> 3) & 3);
                gload_lds16(base + gir2 * 8, ldst + 2048);
            }
        }
    };

    bf16* p0 = lds;
    bf16* p1 = lds + SLICE_E;
    bf16* p2 = lds + 2 * SLICE_E;
    stage(d0 + 0, p0);
    stage(d0 + 1, p1);
    stage(d0 + 2, p2);
    __syncthreads();

    const short8* Wv = (const short8*)Wb;
    float bv = bias[0];

    for (int i = 0; i < 3; ++i) {
        f32x4 acc[4] = {};

        auto compute_dz = [&](const bf16* P, int dz) {
#pragma unroll
            for (int dx = 0; dx < 3; ++dx) {
                const bf16* Ar = P + (wv + dx) * ROW;
#pragma unroll
                for (int dy = 0; dy < 3; ++dy) {
                    int tap = dz * 9 + dy * 3 + dx;
                    short8 b = Wv[tap * 64 + arow * 4 + kg];
                    int hh = arow + dy;
                    int s0 = (hh * 4 + kg) ^ ((hh >> 1) & 3);
#pragma unroll
                    for (int t = 0; t < 4; ++t) {
                        short8 a = *(const short8*)(Ar + s0 * 8 + t * 512);
                        acc[t] = __builtin_amdgcn_mfma_f32_16x16x32_bf16(
                            a, b, acc[t], 0, 0, 0);
                    }
                }
            }
        };

        compute_dz(p0, 0);
        __syncthreads();
        if (i < 2) stage(d0 + i + 3, p0);
        compute_dz(p1, 1);
        compute_dz(p2, 2);

        if (arow == 0) {
            int d = d0 + i;
#pragma unroll
            for (int t = 0; t < 4; ++t)
#pragma unroll
                for (int rr = 0; rr < 4; ++rr) {
                    int o = t * 16 + kg * 4 + rr;
                    out[((size_t)d * HH + o) * WW + (w0 + wv)] = acc[t][rr] + bv;
                }
        }
        __syncthreads();
        bf16* tswap = p0; p0 = p1; p1 = p2; p2 = tswap;
    }
}

// ---------------------------------------------------------------------------
// Launch
// ---------------------------------------------------------------------------
extern "C" void kernel_launch(void* const* d_in, const int* in_sizes, int n_in,
                              void* d_out, int out_size, void* d_ws, size_t ws_size,
                              hipStream_t stream) {
    const float* left  = (const float*)d_in[0];
    const float* right = (const float*)d_in[1];
    const float* w0 = (const float*)d_in[2];
    const float* b0 = (const float*)d_in[3];
    const float* w1 = (const float*)d_in[4];
    const float* b1 = (const float*)d_in[5];
    const float* w2 = (const float*)d_in[6];
    const float* b2 = (const float*)d_in[7];
    const float* w3 = (const float*)d_in[8];
    const float* b3 = (const float*)d_in[9];
    const float* wf = (const float*)d_in[10];
    const float* bf = (const float*)d_in[11];

    bf16* volA = (bf16*)d_ws;
    bf16* volB = volA + PVOL;
    bf16* wb0  = volB + PVOL;
    bf16* wb1  = wb0 + 27648;
    bf16* wb2  = wb1 + 27648;
    bf16* wb3  = wb2 + 27648;
    bf16* wbf  = wb3 + 27648;                 // 13824 elems
    float* Lt  = (float*)(wbf + 13824 + 32);  // 16B-aligned
    float* Rt  = Lt + FEAT;

    border_zero_kernel<<<(2 * BORDER_ELEMS + 255) / 256, 256, 0, stream>>>(volA, volB);

    convert_w_mid4_kernel<<<432, 256, 0, stream>>>(w0, w1, w2, w3, wb0, wb1, wb2, wb3);
    convert_w_final_kernel<<<54, 256, 0, stream>>>(wf, wbf);

    transpose_feat_kernel<<<dim3(WW / 32, HH, 2), 256, 0, stream>>>(left, right, Lt, Rt);

    build_vol_kernel<<<dim3(WW / 8, HH), 256, 0, stream>>>(Lt, Rt, volA);

    int grid = 512;   // 32 w-quads x 16 d-segments, all-resident (2 blocks/CU)
    conv_mid_kernel<<<grid, 256, 0, stream>>>(volA, wb0, b0, volB);
    conv_mid_kernel<<<grid, 256, 0, stream>>>(volB, wb1, b1, volA);
    conv_mid_kernel<<<grid, 256, 0, stream>>>(volA, wb2, b2, volB);
    conv_mid_kernel<<<grid, 256, 0, stream>>>(volB, wb3, b3, volA);
    conv_final_kernel<<<grid, 256, 0, stream>>>(volA, wbf, bf, (float*)d_out);
}

// Round 14
// 188.868 us; speedup vs baseline: 2.7363x; 1.0036x over previous
//
#include <hip/hip_runtime.h>
#include <hip/hip_bf16.h>

// Problem constants
#define HH 64
#define WW 128
#define DD 48
#define CG 8
// Padded volume layout: [d 50][w 130][h 66][c 32]  (channels-last, h inner)
#define PD 50
#define PWp 130
#define PHp 66
#define ROW 2112                               // elems per (d,w) row = 66*32
#define PVOL ((size_t)PD * PWp * ROW)          // 13,728,000 elems
#define FEAT ((size_t)HH * WW * 256)
#define SLICE_E (6 * ROW)                      // 12672 elems = 25344 B

typedef __hip_bfloat16 bf16;
typedef __attribute__((ext_vector_type(8))) short short8;
typedef __attribute__((ext_vector_type(4))) float f32x4;

__device__ __forceinline__ void gload_lds16(const bf16* g, bf16* l) {
    __builtin_amdgcn_global_load_lds(
        (const __attribute__((address_space(1))) unsigned int*)g,
        (__attribute__((address_space(3))) unsigned int*)l, 16, 0, 0);
}

// ---------------------------------------------------------------------------
// Border zeroing of both padded volumes
// ---------------------------------------------------------------------------
#define BORDER_ELEMS 1145088
__global__ __launch_bounds__(256) void border_zero_kernel(bf16* __restrict__ volA,
                                                          bf16* __restrict__ volB) {
    size_t tid = (size_t)blockIdx.x * 256 + threadIdx.x;
    if (tid >= 2 * (size_t)BORDER_ELEMS) return;
    bf16* vol = (tid >= BORDER_ELEMS) ? volB : volA;
    size_t i = (tid >= BORDER_ELEMS) ? tid - BORDER_ELEMS : tid;
    size_t addr;
    if (i < 549120) {                       // d slices 0 and 49
        int dsl = (i < 274560) ? 0 : 49;
        size_t rem = i % 274560;
        addr = (size_t)dsl * PWp * ROW + rem;
    } else if (i < 751872) {                // w cols 0 and 129, d 1..48
        size_t j = i - 549120;
        int dd = (int)(j / 4224);
        int rr = (int)(j % 4224);
        int wcol = (rr < ROW) ? 0 : 129;
        int off = (rr < ROW) ? rr : rr - ROW;
        addr = ((size_t)(dd + 1) * PWp + wcol) * ROW + off;
    } else {                                // h rows 0 and 65, d 1..48, w 1..128
        size_t j = i - 751872;
        int dd = (int)(j >> 13);
        int rr = (int)(j & 8191);
        int w = rr >> 6;
        int e = rr & 63;
        int hrow = (e < 32) ? 0 : 65;
        addr = ((size_t)(dd + 1) * PWp + (w + 1)) * ROW + hrow * 32 + (e & 31);
    }
    vol[addr] = __float2bfloat16(0.f);
}

// ---------------------------------------------------------------------------
// Feature transpose (L and R fused via blockIdx.z):
// [256][64][128] f32 -> [64][128][256] f32
// ---------------------------------------------------------------------------
__global__ __launch_bounds__(256) void transpose_feat_kernel(
    const float* __restrict__ L, const float* __restrict__ R,
    float* __restrict__ Lt, float* __restrict__ Rt) {
    __shared__ float tile[32][257];
    const float* src = blockIdx.z ? R : L;
    float* dst       = blockIdx.z ? Rt : Lt;
    int tid = threadIdx.x;
    int w0  = blockIdx.x * 32;
    int h   = blockIdx.y;

#pragma unroll
    for (int it = 0; it < 32; ++it) {
        int c = it * 8 + (tid >> 5);
        tile[tid & 31][c] =
            src[(size_t)c * (HH * WW) + h * WW + w0 + (tid & 31)];
    }
    __syncthreads();

    int c_l = tid & 63, wg = tid >> 6;
#pragma unroll
    for (int it = 0; it < 8; ++it) {
        int w_i = it * 4 + wg;
        float* dp = dst + ((size_t)h * WW + w0 + w_i) * 256;
#pragma unroll
        for (int cc = 0; cc < 256; cc += 64)
            dp[cc + c_l] = tile[w_i][cc + c_l];
    }
}

// ---------------------------------------------------------------------------
// Weight conversion, all 5 layers in one dispatch:
// mid: fp32 [32][32][27] -> bf16 [tap][co][ci]; final -> [tap][co<16][ci]
// ---------------------------------------------------------------------------
__global__ void convert_w_all_kernel(const float* __restrict__ s0,
                                     const float* __restrict__ s1,
                                     const float* __restrict__ s2,
                                     const float* __restrict__ s3,
                                     const float* __restrict__ sf,
                                     bf16* __restrict__ d0, bf16* __restrict__ d1,
                                     bf16* __restrict__ d2, bf16* __restrict__ d3,
                                     bf16* __restrict__ df) {
    int tid = blockIdx.x * 256 + threadIdx.x;
    if (tid < 4 * 27648) {
        int layer = tid / 27648;
        int t = tid % 27648;
        const float* src = layer == 0 ? s0 : layer == 1 ? s1 : layer == 2 ? s2 : s3;
        bf16* dst = layer == 0 ? d0 : layer == 1 ? d1 : layer == 2 ? d2 : d3;
        int tap = t >> 10, co = (t >> 5) & 31, ci = t & 31;
        dst[t] = __float2bfloat16(src[(co * 32 + ci) * 27 + tap]);
    } else if (tid < 4 * 27648 + 27 * 16 * 32) {
        int t = tid - 4 * 27648;
        int tap = t >> 9;
        int co  = (t >> 5) & 15;
        int ci  = t & 31;
        df[t] = (co == 0) ? __float2bfloat16(sf[ci * 27 + tap])
                          : __float2bfloat16(0.f);
    }
}

// ---------------------------------------------------------------------------
// Cost volume from channels-last features -> padded [d][w][h][c] bf16
// ---------------------------------------------------------------------------
__global__ __launch_bounds__(256) void build_vol_kernel(
    const float* __restrict__ Lt, const float* __restrict__ Rt,
    bf16* __restrict__ vol) {
    int g  = threadIdx.x & 31;
    int wq = threadIdx.x >> 5;
    int w  = blockIdx.x * 8 + wq;
    int h  = blockIdx.y;

    const float4* lp = (const float4*)(Lt + ((size_t)h * WW + w) * 256 + g * 8);
    float4 l0 = lp[0], l1 = lp[1];
    const float* Rrow = Rt + (size_t)h * WW * 256;

    bf16* outp = vol + ((size_t)1 * PWp + (w + 1)) * ROW + (h + 1) * 32 + g;
    for (int d = 0; d < DD; ++d) {
        int x = w - d;
        float s = 0.f;
        if (x >= 0) {
            const float4* rp = (const float4*)(Rrow + (size_t)x * 256 + g * 8);
            float4 r0 = rp[0], r1 = rp[1];
            s = l0.x * r0.x + l0.y * r0.y + l0.z * r0.z + l0.w * r0.w +
                l1.x * r1.x + l1.y * r1.y + l1.z * r1.z + l1.w * r1.w;
            s *= 0.125f;
        }
        outp[(size_t)d * PWp * ROW] = __float2bfloat16(s);
    }
}

// ---------------------------------------------------------------------------
// Mid conv, pipelined d-walk (r10/r13 structure EXACTLY: 256 thr / 4 waves,
// grid 512 = (w-quad, d-segment of 3), full-h 25 KB slices, 76 KB ring,
// 2 blocks/CU, dz-split async refill).
// NEW r14: co-tile-0 B-fragments (27 x short8 = 108 VGPR) hoisted into
// registers once per layer -- halves the per-step L1 weight traffic.
// Swizzle involution f(s)=s^((s>>3)&3) on global source; reads use
// slot=(hh*4+kg)^((hh>>1)&3). Verified r5/r6: 0 bank conflicts.
// ---------------------------------------------------------------------------
__global__ __launch_bounds__(256, 2) void conv_mid_kernel(
    const bf16* __restrict__ X, const bf16* __restrict__ Wb,
    const float* __restrict__ bias, bf16* __restrict__ Y) {
    __shared__ bf16 lds[3 * SLICE_E];
    int id   = blockIdx.x;
    int xcd  = id & 7;
    int r    = id >> 3;                  // 0..63
    int wq   = r & 31;
    int dseg = xcd * 2 + (r >> 5);       // blocks sharing slices land on same XCD
    int w0   = wq * 4;
    int d0   = dseg * 3;
    int tid  = threadIdx.x;
    int wv   = tid >> 6;
    int lane = tid & 63;
    int arow = lane & 15;
    int kg   = lane >> 4;

    auto stage = [&](int dslice, bf16* dst) {
#pragma unroll
        for (int row = 0; row < 6; ++row) {
            const bf16* base = X + ((size_t)dslice * PWp + (w0 + row)) * ROW;
            bf16* ldst = dst + row * ROW;
            int s = wv * 64 + lane;
            int gir = s ^ ((s >> 3) & 3);
            gload_lds16(base + gir * 8, ldst + wv * 512);
            if (tid < 8) {
                int s2 = 256 + lane;
                int gir2 = s2 ^ ((s2 >> 3) & 3);
                gload_lds16(base + gir2 * 8, ldst + 2048);
            }
        }
    };

    bf16* p0 = lds;
    bf16* p1 = lds + SLICE_E;
    bf16* p2 = lds + 2 * SLICE_E;
    stage(d0 + 0, p0);
    stage(d0 + 1, p1);
    stage(d0 + 2, p2);

    const short8* Wv = (const short8*)Wb;
    // Hoist co-tile-0 B-fragments for all 27 taps (108 VGPRs, layer-invariant)
    short8 B0[27];
#pragma unroll
    for (int tap = 0; tap < 27; ++tap)
        B0[tap] = Wv[tap * 128 + arow * 4 + kg];

    __syncthreads();

    float bv0 = bias[arow];
    float bv1 = bias[arow + 16];

    for (int i = 0; i < 3; ++i) {
        f32x4 acc[4][2] = {};

        // accumulate one dz-slice worth of taps from ring slot P
        auto compute_dz = [&](const bf16* P, int dz) {
#pragma unroll
            for (int dx = 0; dx < 3; ++dx) {
                const bf16* Ar = P + (wv + dx) * ROW;
#pragma unroll
                for (int dy = 0; dy < 3; ++dy) {
                    int tap = dz * 9 + dy * 3 + dx;
                    short8 b1 = Wv[tap * 128 + 64 + arow * 4 + kg];
                    int hh = arow + dy;
                    int s0 = (hh * 4 + kg) ^ ((hh >> 1) & 3);
#pragma unroll
                    for (int t = 0; t < 4; ++t) {
                        short8 a = *(const short8*)(Ar + s0 * 8 + t * 512);
                        acc[t][0] = __builtin_amdgcn_mfma_f32_16x16x32_bf16(
                            a, B0[tap], acc[t][0], 0, 0, 0);
                        acc[t][1] = __builtin_amdgcn_mfma_f32_16x16x32_bf16(
                            a, b1, acc[t][1], 0, 0, 0);
                    }
                }
            }
        };

        // Phase A: dz=0 -- sole reader of p0
        compute_dz(p0, 0);
        __syncthreads();                       // all waves done with p0
        if (i < 2) stage(d0 + i + 3, p0);      // async refill into freed slot
        // Phase B: dz=1,2 -- stage latency hides under this
        compute_dz(p1, 1);
        compute_dz(p2, 2);

        int d = d0 + i;
        bf16* Yp = Y + (((size_t)(d + 1) * PWp + (w0 + wv + 1))) * ROW + 32;
#pragma unroll
        for (int t = 0; t < 4; ++t)
#pragma unroll
            for (int rr = 0; rr < 4; ++rr) {
                int o = t * 16 + kg * 4 + rr;
                float v0 = acc[t][0][rr] + bv0;
                float v1 = acc[t][1][rr] + bv1;
                v0 = fmaxf(v0, 0.f) + 0.2f * fminf(v0, 0.f);
                v1 = fmaxf(v1, 0.f) + 0.2f * fminf(v1, 0.f);
                Yp[o * 32 + arow]      = __float2bfloat16(v0);
                Yp[o * 32 + arow + 16] = __float2bfloat16(v1);
            }
        __syncthreads();                       // vmcnt(0) drained here: slice landed
        bf16* tswap = p0; p0 = p1; p1 = p2; p2 = tswap;
    }
}

// ---------------------------------------------------------------------------
// Final conv (32ch -> 1), same structure; all 27 B-frags hoisted. fp32 out.
// ---------------------------------------------------------------------------
__global__ __launch_bounds__(256, 2) void conv_final_kernel(
    const bf16* __restrict__ X, const bf16* __restrict__ Wb,
    const float* __restrict__ bias, float* __restrict__ out) {
    __shared__ bf16 lds[3 * SLICE_E];
    int id   = blockIdx.x;
    int xcd  = id & 7;
    int r    = id >> 3;
    int wq   = r & 31;
    int dseg = xcd * 2 + (r >> 5);
    int w0   = wq * 4;
    int d0   = dseg * 3;
    int tid  = threadIdx.x;
    int wv   = tid >> 6;
    int lane = tid & 63;
    int arow = lane & 15;
    int kg   = lane >> 4;

    auto stage = [&](int dslice, bf16* dst) {
#pragma unroll
        for (int row = 0; row < 6; ++row) {
            const bf16* base = X + ((size_t)dslice * PWp + (w0 + row)) * ROW;
            bf16* ldst = dst + row * ROW;
            int s = wv * 64 + lane;
            int gir = s ^ ((s >> 3) & 3);
            gload_lds16(base + gir * 8, ldst + wv * 512);
            if (tid < 8) {
                int s2 = 256 + lane;
                int gir2 = s2 ^ ((s2 >> 3) & 3);
                gload_lds16(base + gir2 * 8, ldst + 2048);
            }
        }
    };

    bf16* p0 = lds;
    bf16* p1 = lds + SLICE_E;
    bf16* p2 = lds + 2 * SLICE_E;
    stage(d0 + 0, p0);
    stage(d0 + 1, p1);
    stage(d0 + 2, p2);

    const short8* Wv = (const short8*)Wb;
    short8 B0[27];
#pragma unroll
    for (int tap = 0; tap < 27; ++tap)
        B0[tap] = Wv[tap * 64 + arow * 4 + kg];

    __syncthreads();

    float bv = bias[0];

    for (int i = 0; i < 3; ++i) {
        f32x4 acc[4] = {};

        auto compute_dz = [&](const bf16* P, int dz) {
#pragma unroll
            for (int dx = 0; dx < 3; ++dx) {
                const bf16* Ar = P + (wv + dx) * ROW;
#pragma unroll
                for (int dy = 0; dy < 3; ++dy) {
                    int tap = dz * 9 + dy * 3 + dx;
                    int hh = arow + dy;
                    int s0 = (hh * 4 + kg) ^ ((hh >> 1) & 3);
#pragma unroll
                    for (int t = 0; t < 4; ++t) {
                        short8 a = *(const short8*)(Ar + s0 * 8 + t * 512);
                        acc[t] = __builtin_amdgcn_mfma_f32_16x16x32_bf16(
                            a, B0[tap], acc[t], 0, 0, 0);
                    }
                }
            }
        };

        compute_dz(p0, 0);
        __syncthreads();
        if (i < 2) stage(d0 + i + 3, p0);
        compute_dz(p1, 1);
        compute_dz(p2, 2);

        if (arow == 0) {
            int d = d0 + i;
#pragma unroll
            for (int t = 0; t < 4; ++t)
#pragma unroll
                for (int rr = 0; rr < 4; ++rr) {
                    int o = t * 16 + kg * 4 + rr;
                    out[((size_t)d * HH + o) * WW + (w0 + wv)] = acc[t][rr] + bv;
                }
        }
        __syncthreads();
        bf16* tswap = p0; p0 = p1; p1 = p2; p2 = tswap;
    }
}

// ---------------------------------------------------------------------------
// Launch
// ---------------------------------------------------------------------------
extern "C" void kernel_launch(void* const* d_in, const int* in_sizes, int n_in,
                              void* d_out, int out_size, void* d_ws, size_t ws_size,
                              hipStream_t stream) {
    const float* left  = (const float*)d_in[0];
    const float* right = (const float*)d_in[1];
    const float* w0 = (const float*)d_in[2];
    const float* b0 = (const float*)d_in[3];
    const float* w1 = (const float*)d_in[4];
    const float* b1 = (const float*)d_in[5];
    const float* w2 = (const float*)d_in[6];
    const float* b2 = (const float*)d_in[7];
    const float* w3 = (const float*)d_in[8];
    const float* b3 = (const float*)d_in[9];
    const float* wf = (const float*)d_in[10];
    const float* bf = (const float*)d_in[11];

    bf16* volA = (bf16*)d_ws;
    bf16* volB = volA + PVOL;
    bf16* wb0  = volB + PVOL;
    bf16* wb1  = wb0 + 27648;
    bf16* wb2  = wb1 + 27648;
    bf16* wb3  = wb2 + 27648;
    bf16* wbf  = wb3 + 27648;                 // 13824 elems
    float* Lt  = (float*)(wbf + 13824 + 32);  // 16B-aligned
    float* Rt  = Lt + FEAT;

    border_zero_kernel<<<(2 * BORDER_ELEMS + 255) / 256, 256, 0, stream>>>(volA, volB);

    convert_w_all_kernel<<<486, 256, 0, stream>>>(w0, w1, w2, w3, wf,
                                                  wb0, wb1, wb2, wb3, wbf);

    transpose_feat_kernel<<<dim3(WW / 32, HH, 2), 256, 0, stream>>>(left, right, Lt, Rt);

    build_vol_kernel<<<dim3(WW / 8, HH), 256, 0, stream>>>(Lt, Rt, volA);

    int grid = 512;   // 32 w-quads x 16 d-segments, all-resident (2 blocks/CU)
    conv_mid_kernel<<<grid, 256, 0, stream>>>(volA, wb0, b0, volB);
    conv_mid_kernel<<<grid, 256, 0, stream>>>(volB, wb1, b1, volA);
    conv_mid_kernel<<<grid, 256, 0, stream>>>(volA, wb2, b2, volB);
    conv_mid_kernel<<<grid, 256, 0, stream>>>(volB, wb3, b3, volA);
    conv_final_kernel<<<grid, 256, 0, stream>>>(volA, wbf, bf, (float*)d_out);
}

// Round 15
// 184.227 us; speedup vs baseline: 2.8052x; 1.0252x over previous
//
#include <hip/hip_runtime.h>
#include <hip/hip_bf16.h>

// Problem constants
#define HH 64
#define WW 128
#define DD 48
#define CG 8
// Padded volume layout: [d 50][w 130][h 66][c 32]  (channels-last, h inner)
#define PD 50
#define PWp 130
#define PHp 66
#define ROW 2112                               // elems per (d,w) row = 66*32
#define PVOL ((size_t)PD * PWp * ROW)          // 13,728,000 elems
#define FEAT ((size_t)HH * WW * 256)
#define SLICE_E (6 * ROW)                      // 12672 elems = 25344 B

typedef __hip_bfloat16 bf16;
typedef __attribute__((ext_vector_type(8))) short short8;
typedef __attribute__((ext_vector_type(4))) float f32x4;

__device__ __forceinline__ void gload_lds16(const bf16* g, bf16* l) {
    __builtin_amdgcn_global_load_lds(
        (const __attribute__((address_space(1))) unsigned int*)g,
        (__attribute__((address_space(3))) unsigned int*)l, 16, 0, 0);
}
__device__ __forceinline__ void gload_lds16f(const float* g, float* l) {
    __builtin_amdgcn_global_load_lds(
        (const __attribute__((address_space(1))) unsigned int*)g,
        (__attribute__((address_space(3))) unsigned int*)l, 16, 0, 0);
}

// ---------------------------------------------------------------------------
// Border zeroing of both padded volumes
// ---------------------------------------------------------------------------
#define BORDER_ELEMS 1145088
__global__ __launch_bounds__(256) void border_zero_kernel(bf16* __restrict__ volA,
                                                          bf16* __restrict__ volB) {
    size_t tid = (size_t)blockIdx.x * 256 + threadIdx.x;
    if (tid >= 2 * (size_t)BORDER_ELEMS) return;
    bf16* vol = (tid >= BORDER_ELEMS) ? volB : volA;
    size_t i = (tid >= BORDER_ELEMS) ? tid - BORDER_ELEMS : tid;
    size_t addr;
    if (i < 549120) {                       // d slices 0 and 49
        int dsl = (i < 274560) ? 0 : 49;
        size_t rem = i % 274560;
        addr = (size_t)dsl * PWp * ROW + rem;
    } else if (i < 751872) {                // w cols 0 and 129, d 1..48
        size_t j = i - 549120;
        int dd = (int)(j / 4224);
        int rr = (int)(j % 4224);
        int wcol = (rr < ROW) ? 0 : 129;
        int off = (rr < ROW) ? rr : rr - ROW;
        addr = ((size_t)(dd + 1) * PWp + wcol) * ROW + off;
    } else {                                // h rows 0 and 65, d 1..48, w 1..128
        size_t j = i - 751872;
        int dd = (int)(j >> 13);
        int rr = (int)(j & 8191);
        int w = rr >> 6;
        int e = rr & 63;
        int hrow = (e < 32) ? 0 : 65;
        addr = ((size_t)(dd + 1) * PWp + (w + 1)) * ROW + hrow * 32 + (e & 31);
    }
    vol[addr] = __float2bfloat16(0.f);
}

// ---------------------------------------------------------------------------
// Feature transpose (L/R via blockIdx.z 0/1) + weight conversion (z==2):
// [256][64][128] f32 -> [64][128][256] f32 ; weights -> bf16 [tap][co][ci]
// ---------------------------------------------------------------------------
__global__ __launch_bounds__(256) void transpose_feat_kernel(
    const float* __restrict__ L, const float* __restrict__ R,
    float* __restrict__ Lt, float* __restrict__ Rt,
    const float* __restrict__ s0, const float* __restrict__ s1,
    const float* __restrict__ s2, const float* __restrict__ s3,
    const float* __restrict__ sf,
    bf16* __restrict__ wbm, bf16* __restrict__ wbf) {
    __shared__ float tile[32][257];
    int tid = threadIdx.x;

    if (blockIdx.z == 2) {                   // weight conversion plane
        int flat = (blockIdx.y * 4 + blockIdx.x) * 256 + tid;   // [0, 65536)
#pragma unroll
        for (int pass = 0; pass < 2; ++pass) {
            int e = flat + pass * 65536;
            if (e < 4 * 27648) {             // mid weights (wbm contiguous)
                int layer = e / 27648;
                int t = e % 27648;
                const float* src = layer == 0 ? s0 : layer == 1 ? s1
                                 : layer == 2 ? s2 : s3;
                int tap = t >> 10, co = (t >> 5) & 31, ci = t & 31;
                wbm[e] = __float2bfloat16(src[(co * 32 + ci) * 27 + tap]);
            } else if (e < 4 * 27648 + 27 * 16 * 32) {
                int t = e - 4 * 27648;
                int tap = t >> 9;
                int co  = (t >> 5) & 15;
                int ci  = t & 31;
                wbf[t] = (co == 0) ? __float2bfloat16(sf[ci * 27 + tap])
                                   : __float2bfloat16(0.f);
            }
        }
        return;
    }

    const float* src = blockIdx.z ? R : L;
    float* dst       = blockIdx.z ? Rt : Lt;
    int w0  = blockIdx.x * 32;
    int h   = blockIdx.y;

#pragma unroll
    for (int it = 0; it < 32; ++it) {
        int c = it * 8 + (tid >> 5);
        tile[tid & 31][c] =
            src[(size_t)c * (HH * WW) + h * WW + w0 + (tid & 31)];
    }
    __syncthreads();

    int c_l = tid & 63, wg = tid >> 6;
#pragma unroll
    for (int it = 0; it < 8; ++it) {
        int w_i = it * 4 + wg;
        float* dp = dst + ((size_t)h * WW + w0 + w_i) * 256;
#pragma unroll
        for (int cc = 0; cc < 256; cc += 64)
            dp[cc + c_l] = tile[w_i][cc + c_l];
    }
}

// ---------------------------------------------------------------------------
// Cost volume v2: R-window staged in LDS.
// Block = (8 w, 1 h): needs R x-range [max(0,w0-47), w0+8) <= 55 KB fp32,
// contiguous in Rt -> global_load_lds. d-loop then reads LDS (was L2).
// ---------------------------------------------------------------------------
__global__ __launch_bounds__(256) void build_vol_kernel(
    const float* __restrict__ Lt, const float* __restrict__ Rt,
    bf16* __restrict__ vol) {
    __shared__ float rwin[55 * 256];         // 56,320 B
    int tid = threadIdx.x;
    int g  = tid & 31;
    int wq = tid >> 5;
    int w  = blockIdx.x * 8 + wq;
    int h  = blockIdx.y;
    int w0 = blockIdx.x * 8;

    int sx = w0 - 47; if (sx < 0) sx = 0;
    int cnt = w0 + 8 - sx;                   // x-rows staged (<= 55)
    const float* Rbase = Rt + ((size_t)h * WW + sx) * 256;

    // stage cnt*1024 bytes: 256 threads x 16 B = 4 KB (4 rows) per iter
    int total16 = cnt * 64;                  // 16B-chunks
    for (int it = 0; it < 14; ++it) {
        int c16 = it * 256 + tid;
        if (c16 < total16)
            gload_lds16f(Rbase + c16 * 4, rwin + c16 * 4);
    }

    const float4* lp = (const float4*)(Lt + ((size_t)h * WW + w) * 256 + g * 8);
    float4 l0 = lp[0], l1 = lp[1];
    __syncthreads();

    bf16* outp = vol + ((size_t)1 * PWp + (w + 1)) * ROW + (h + 1) * 32 + g;
    for (int d = 0; d < DD; ++d) {
        int x = w - d;
        float s = 0.f;
        if (x >= 0) {
            const float4* rp = (const float4*)(rwin + (size_t)(x - sx) * 256 + g * 8);
            float4 r0 = rp[0], r1 = rp[1];
            s = l0.x * r0.x + l0.y * r0.y + l0.z * r0.z + l0.w * r0.w +
                l1.x * r1.x + l1.y * r1.y + l1.z * r1.z + l1.w * r1.w;
            s *= 0.125f;
        }
        outp[(size_t)d * PWp * ROW] = __float2bfloat16(s);
    }
}

// ---------------------------------------------------------------------------
// Mid conv, pipelined d-walk (r10/r13/r14 structure EXACTLY: 256 thr / 4
// waves, grid 512 = (w-quad, d-segment of 3), full-h 25 KB slices, 76 KB
// ring, 2 blocks/CU, dz-split async refill, co-tile-0 B-frags hoisted).
// Swizzle involution f(s)=s^((s>>3)&3) on global source; reads use
// slot=(hh*4+kg)^((hh>>1)&3). Verified r5/r6: 0 bank conflicts.
// ---------------------------------------------------------------------------
__global__ __launch_bounds__(256, 2) void conv_mid_kernel(
    const bf16* __restrict__ X, const bf16* __restrict__ Wb,
    const float* __restrict__ bias, bf16* __restrict__ Y) {
    __shared__ bf16 lds[3 * SLICE_E];
    int id   = blockIdx.x;
    int xcd  = id & 7;
    int r    = id >> 3;                  // 0..63
    int wq   = r & 31;
    int dseg = xcd * 2 + (r >> 5);       // blocks sharing slices land on same XCD
    int w0   = wq * 4;
    int d0   = dseg * 3;
    int tid  = threadIdx.x;
    int wv   = tid >> 6;
    int lane = tid & 63;
    int arow = lane & 15;
    int kg   = lane >> 4;

    auto stage = [&](int dslice, bf16* dst) {
#pragma unroll
        for (int row = 0; row < 6; ++row) {
            const bf16* base = X + ((size_t)dslice * PWp + (w0 + row)) * ROW;
            bf16* ldst = dst + row * ROW;
            int s = wv * 64 + lane;
            int gir = s ^ ((s >> 3) & 3);
            gload_lds16(base + gir * 8, ldst + wv * 512);
            if (tid < 8) {
                int s2 = 256 + lane;
                int gir2 = s2 ^ ((s2 >> 3) & 3);
                gload_lds16(base + gir2 * 8, ldst + 2048);
            }
        }
    };

    bf16* p0 = lds;
    bf16* p1 = lds + SLICE_E;
    bf16* p2 = lds + 2 * SLICE_E;
    stage(d0 + 0, p0);
    stage(d0 + 1, p1);
    stage(d0 + 2, p2);

    const short8* Wv = (const short8*)Wb;
    // Hoist co-tile-0 B-fragments for all 27 taps (108 VGPRs, layer-invariant)
    short8 B0[27];
#pragma unroll
    for (int tap = 0; tap < 27; ++tap)
        B0[tap] = Wv[tap * 128 + arow * 4 + kg];

    __syncthreads();

    float bv0 = bias[arow];
    float bv1 = bias[arow + 16];

    for (int i = 0; i < 3; ++i) {
        f32x4 acc[4][2] = {};

        // accumulate one dz-slice worth of taps from ring slot P
        auto compute_dz = [&](const bf16* P, int dz) {
#pragma unroll
            for (int dx = 0; dx < 3; ++dx) {
                const bf16* Ar = P + (wv + dx) * ROW;
#pragma unroll
                for (int dy = 0; dy < 3; ++dy) {
                    int tap = dz * 9 + dy * 3 + dx;
                    short8 b1 = Wv[tap * 128 + 64 + arow * 4 + kg];
                    int hh = arow + dy;
                    int s0 = (hh * 4 + kg) ^ ((hh >> 1) & 3);
#pragma unroll
                    for (int t = 0; t < 4; ++t) {
                        short8 a = *(const short8*)(Ar + s0 * 8 + t * 512);
                        acc[t][0] = __builtin_amdgcn_mfma_f32_16x16x32_bf16(
                            a, B0[tap], acc[t][0], 0, 0, 0);
                        acc[t][1] = __builtin_amdgcn_mfma_f32_16x16x32_bf16(
                            a, b1, acc[t][1], 0, 0, 0);
                    }
                }
            }
        };

        // Phase A: dz=0 -- sole reader of p0
        compute_dz(p0, 0);
        __syncthreads();                       // all waves done with p0
        if (i < 2) stage(d0 + i + 3, p0);      // async refill into freed slot
        // Phase B: dz=1,2 -- stage latency hides under this
        compute_dz(p1, 1);
        compute_dz(p2, 2);

        int d = d0 + i;
        bf16* Yp = Y + (((size_t)(d + 1) * PWp + (w0 + wv + 1))) * ROW + 32;
#pragma unroll
        for (int t = 0; t < 4; ++t)
#pragma unroll
            for (int rr = 0; rr < 4; ++rr) {
                int o = t * 16 + kg * 4 + rr;
                float v0 = acc[t][0][rr] + bv0;
                float v1 = acc[t][1][rr] + bv1;
                v0 = fmaxf(v0, 0.f) + 0.2f * fminf(v0, 0.f);
                v1 = fmaxf(v1, 0.f) + 0.2f * fminf(v1, 0.f);
                Yp[o * 32 + arow]      = __float2bfloat16(v0);
                Yp[o * 32 + arow + 16] = __float2bfloat16(v1);
            }
        __syncthreads();                       // vmcnt(0) drained here: slice landed
        bf16* tswap = p0; p0 = p1; p1 = p2; p2 = tswap;
    }
}

// ---------------------------------------------------------------------------
// Final conv (32ch -> 1), same structure; all 27 B-frags hoisted. fp32 out.
// ---------------------------------------------------------------------------
__global__ __launch_bounds__(256, 2) void conv_final_kernel(
    const bf16* __restrict__ X, const bf16* __restrict__ Wb,
    const float* __restrict__ bias, float* __restrict__ out) {
    __shared__ bf16 lds[3 * SLICE_E];
    int id   = blockIdx.x;
    int xcd  = id & 7;
    int r    = id >> 3;
    int wq   = r & 31;
    int dseg = xcd * 2 + (r >> 5);
    int w0   = wq * 4;
    int d0   = dseg * 3;
    int tid  = threadIdx.x;
    int wv   = tid >> 6;
    int lane = tid & 63;
    int arow = lane & 15;
    int kg   = lane >> 4;

    auto stage = [&](int dslice, bf16* dst) {
#pragma unroll
        for (int row = 0; row < 6; ++row) {
            const bf16* base = X + ((size_t)dslice * PWp + (w0 + row)) * ROW;
            bf16* ldst = dst + row * ROW;
            int s = wv * 64 + lane;
            int gir = s ^ ((s >> 3) & 3);
            gload_lds16(base + gir * 8, ldst + wv * 512);
            if (tid < 8) {
                int s2 = 256 + lane;
                int gir2 = s2 ^ ((s2 >> 3) & 3);
                gload_lds16(base + gir2 * 8, ldst + 2048);
            }
        }
    };

    bf16* p0 = lds;
    bf16* p1 = lds + SLICE_E;
    bf16* p2 = lds + 2 * SLICE_E;
    stage(d0 + 0, p0);
    stage(d0 + 1, p1);
    stage(d0 + 2, p2);

    const short8* Wv = (const short8*)Wb;
    short8 B0[27];
#pragma unroll
    for (int tap = 0; tap < 27; ++tap)
        B0[tap] = Wv[tap * 64 + arow * 4 + kg];

    __syncthreads();

    float bv = bias[0];

    for (int i = 0; i < 3; ++i) {
        f32x4 acc[4] = {};

        auto compute_dz = [&](const bf16* P, int dz) {
#pragma unroll
            for (int dx = 0; dx < 3; ++dx) {
                const bf16* Ar = P + (wv + dx) * ROW;
#pragma unroll
                for (int dy = 0; dy < 3; ++dy) {
                    int tap = dz * 9 + dy * 3 + dx;
                    int hh = arow + dy;
                    int s0 = (hh * 4 + kg) ^ ((hh >> 1) & 3);
#pragma unroll
                    for (int t = 0; t < 4; ++t) {
                        short8 a = *(const short8*)(Ar + s0 * 8 + t * 512);
                        acc[t] = __builtin_amdgcn_mfma_f32_16x16x32_bf16(
                            a, B0[tap], acc[t], 0, 0, 0);
                    }
                }
            }
        };

        compute_dz(p0, 0);
        __syncthreads();
        if (i < 2) stage(d0 + i + 3, p0);
        compute_dz(p1, 1);
        compute_dz(p2, 2);

        if (arow == 0) {
            int d = d0 + i;
#pragma unroll
            for (int t = 0; t < 4; ++t)
#pragma unroll
                for (int rr = 0; rr < 4; ++rr) {
                    int o = t * 16 + kg * 4 + rr;
                    out[((size_t)d * HH + o) * WW + (w0 + wv)] = acc[t][rr] + bv;
                }
        }
        __syncthreads();
        bf16* tswap = p0; p0 = p1; p1 = p2; p2 = tswap;
    }
}

// ---------------------------------------------------------------------------
// Launch
// ---------------------------------------------------------------------------
extern "C" void kernel_launch(void* const* d_in, const int* in_sizes, int n_in,
                              void* d_out, int out_size, void* d_ws, size_t ws_size,
                              hipStream_t stream) {
    const float* left  = (const float*)d_in[0];
    const float* right = (const float*)d_in[1];
    const float* w0 = (const float*)d_in[2];
    const float* b0 = (const float*)d_in[3];
    const float* w1 = (const float*)d_in[4];
    const float* b1 = (const float*)d_in[5];
    const float* w2 = (const float*)d_in[6];
    const float* b2 = (const float*)d_in[7];
    const float* w3 = (const float*)d_in[8];
    const float* b3 = (const float*)d_in[9];
    const float* wf = (const float*)d_in[10];
    const float* bf = (const float*)d_in[11];

    bf16* volA = (bf16*)d_ws;
    bf16* volB = volA + PVOL;
    bf16* wb0  = volB + PVOL;                 // 4 x 27648 contiguous
    bf16* wb1  = wb0 + 27648;
    bf16* wb2  = wb1 + 27648;
    bf16* wb3  = wb2 + 27648;
    bf16* wbf  = wb3 + 27648;                 // 13824 elems
    float* Lt  = (float*)(wbf + 13824 + 32);  // 16B-aligned
    float* Rt  = Lt + FEAT;

    border_zero_kernel<<<(2 * BORDER_ELEMS + 255) / 256, 256, 0, stream>>>(volA, volB);

    transpose_feat_kernel<<<dim3(WW / 32, HH, 3), 256, 0, stream>>>(
        left, right, Lt, Rt, w0, w1, w2, w3, wf, wb0, wbf);

    build_vol_kernel<<<dim3(WW / 8, HH), 256, 0, stream>>>(Lt, Rt, volA);

    int grid = 512;   // 32 w-quads x 16 d-segments, all-resident (2 blocks/CU)
    conv_mid_kernel<<<grid, 256, 0, stream>>>(volA, wb0, b0, volB);
    conv_mid_kernel<<<grid, 256, 0, stream>>>(volB, wb1, b1, volA);
    conv_mid_kernel<<<grid, 256, 0, stream>>>(volA, wb2, b2, volB);
    conv_mid_kernel<<<grid, 256, 0, stream>>>(volB, wb3, b3, volA);
    conv_final_kernel<<<grid, 256, 0, stream>>>(volA, wbf, bf, (float*)d_out);
}

// Round 16
// 180.715 us; speedup vs baseline: 2.8597x; 1.0194x over previous
//
#include <hip/hip_runtime.h>
#include <hip/hip_bf16.h>

// Problem constants
#define HH 64
#define WW 128
#define DD 48
#define CG 8
// Padded volume layout: [d 50][w 130][h 66][c 32]  (channels-last, h inner)
#define PD 50
#define PWp 130
#define PHp 66
#define ROW 2112                               // elems per (d,w) row = 66*32
#define PVOL ((size_t)PD * PWp * ROW)          // 13,728,000 elems
#define FEAT ((size_t)HH * WW * 256)
#define SLICE_E (6 * ROW)                      // 12672 elems = 25344 B
#define BORDER_ELEMS 1145088

typedef __hip_bfloat16 bf16;
typedef __attribute__((ext_vector_type(8))) short short8;
typedef __attribute__((ext_vector_type(4))) float f32x4;

__device__ __forceinline__ void gload_lds16(const bf16* g, bf16* l) {
    __builtin_amdgcn_global_load_lds(
        (const __attribute__((address_space(1))) unsigned int*)g,
        (__attribute__((address_space(3))) unsigned int*)l, 16, 0, 0);
}
__device__ __forceinline__ void gload_lds16f(const float* g, float* l) {
    __builtin_amdgcn_global_load_lds(
        (const __attribute__((address_space(1))) unsigned int*)g,
        (__attribute__((address_space(3))) unsigned int*)l, 16, 0, 0);
}

// Border element index -> address in a padded volume (r13-verified decode)
__device__ __forceinline__ size_t border_addr(size_t i) {
    size_t addr;
    if (i < 549120) {                       // d slices 0 and 49
        int dsl = (i < 274560) ? 0 : 49;
        size_t rem = i % 274560;
        addr = (size_t)dsl * PWp * ROW + rem;
    } else if (i < 751872) {                // w cols 0 and 129, d 1..48
        size_t j = i - 549120;
        int dd = (int)(j / 4224);
        int rr = (int)(j % 4224);
        int wcol = (rr < ROW) ? 0 : 129;
        int off = (rr < ROW) ? rr : rr - ROW;
        addr = ((size_t)(dd + 1) * PWp + wcol) * ROW + off;
    } else {                                // h rows 0 and 65, d 1..48, w 1..128
        size_t j = i - 751872;
        int dd = (int)(j >> 13);
        int rr = (int)(j & 8191);
        int w = rr >> 6;
        int e = rr & 63;
        int hrow = (e < 32) ? 0 : 65;
        addr = ((size_t)(dd + 1) * PWp + (w + 1)) * ROW + hrow * 32 + (e & 31);
    }
    return addr;
}

// ---------------------------------------------------------------------------
// Feature transpose (L/R via blockIdx.z 0/1) + weight conversion (z==2):
// [256][64][128] f32 -> [64][128][256] f32 ; weights -> bf16 [tap][co][ci]
// ---------------------------------------------------------------------------
__global__ __launch_bounds__(256) void transpose_feat_kernel(
    const float* __restrict__ L, const float* __restrict__ R,
    float* __restrict__ Lt, float* __restrict__ Rt,
    const float* __restrict__ s0, const float* __restrict__ s1,
    const float* __restrict__ s2, const float* __restrict__ s3,
    const float* __restrict__ sf,
    bf16* __restrict__ wbm, bf16* __restrict__ wbf) {
    __shared__ float tile[32][257];
    int tid = threadIdx.x;

    if (blockIdx.z == 2) {                   // weight conversion plane
        int flat = (blockIdx.y * 4 + blockIdx.x) * 256 + tid;   // [0, 65536)
#pragma unroll
        for (int pass = 0; pass < 2; ++pass) {
            int e = flat + pass * 65536;
            if (e < 4 * 27648) {             // mid weights (wbm contiguous)
                int layer = e / 27648;
                int t = e % 27648;
                const float* src = layer == 0 ? s0 : layer == 1 ? s1
                                 : layer == 2 ? s2 : s3;
                int tap = t >> 10, co = (t >> 5) & 31, ci = t & 31;
                wbm[e] = __float2bfloat16(src[(co * 32 + ci) * 27 + tap]);
            } else if (e < 4 * 27648 + 27 * 16 * 32) {
                int t = e - 4 * 27648;
                int tap = t >> 9;
                int co  = (t >> 5) & 15;
                int ci  = t & 31;
                wbf[t] = (co == 0) ? __float2bfloat16(sf[ci * 27 + tap])
                                   : __float2bfloat16(0.f);
            }
        }
        return;
    }

    const float* src = blockIdx.z ? R : L;
    float* dst       = blockIdx.z ? Rt : Lt;
    int w0  = blockIdx.x * 32;
    int h   = blockIdx.y;

#pragma unroll
    for (int it = 0; it < 32; ++it) {
        int c = it * 8 + (tid >> 5);
        tile[tid & 31][c] =
            src[(size_t)c * (HH * WW) + h * WW + w0 + (tid & 31)];
    }
    __syncthreads();

    int c_l = tid & 63, wg = tid >> 6;
#pragma unroll
    for (int it = 0; it < 8; ++it) {
        int w_i = it * 4 + wg;
        float* dp = dst + ((size_t)h * WW + w0 + w_i) * 256;
#pragma unroll
        for (int cc = 0; cc < 256; cc += 64)
            dp[cc + c_l] = tile[w_i][cc + c_l];
    }
}

// ---------------------------------------------------------------------------
// Cost volume v2 + fused border zeroing of BOTH padded volumes.
// R-window staged in LDS (r15-verified). Border tail loop: 262,144 threads
// cover 2*BORDER_ELEMS scattered zero-writes (<=9 per thread); addresses
// disjoint from interior stores; consumers are downstream conv dispatches.
// ---------------------------------------------------------------------------
__global__ __launch_bounds__(256) void build_vol_kernel(
    const float* __restrict__ Lt, const float* __restrict__ Rt,
    bf16* __restrict__ volA, bf16* __restrict__ volB) {
    __shared__ float rwin[55 * 256];         // 56,320 B
    int tid = threadIdx.x;
    int g  = tid & 31;
    int wq = tid >> 5;
    int w  = blockIdx.x * 8 + wq;
    int h  = blockIdx.y;
    int w0 = blockIdx.x * 8;

    int sx = w0 - 47; if (sx < 0) sx = 0;
    int cnt = w0 + 8 - sx;                   // x-rows staged (<= 55)
    const float* Rbase = Rt + ((size_t)h * WW + sx) * 256;

    // stage cnt*1024 bytes: 256 threads x 16 B = 4 KB (4 rows) per iter
    int total16 = cnt * 64;                  // 16B-chunks
    for (int it = 0; it < 14; ++it) {
        int c16 = it * 256 + tid;
        if (c16 < total16)
            gload_lds16f(Rbase + c16 * 4, rwin + c16 * 4);
    }

    const float4* lp = (const float4*)(Lt + ((size_t)h * WW + w) * 256 + g * 8);
    float4 l0 = lp[0], l1 = lp[1];

    // border zeroing tail (overlaps with staging latency)
    {
        const bf16 z = __float2bfloat16(0.f);
        size_t gid = ((size_t)blockIdx.y * gridDim.x + blockIdx.x) * 256 + tid;
        for (size_t j = gid; j < 2 * (size_t)BORDER_ELEMS; j += 262144) {
            bf16* vv = (j >= BORDER_ELEMS) ? volB : volA;
            size_t i = (j >= BORDER_ELEMS) ? j - BORDER_ELEMS : j;
            vv[border_addr(i)] = z;
        }
    }
    __syncthreads();

    bf16* outp = volA + ((size_t)1 * PWp + (w + 1)) * ROW + (h + 1) * 32 + g;
    for (int d = 0; d < DD; ++d) {
        int x = w - d;
        float s = 0.f;
        if (x >= 0) {
            const float4* rp = (const float4*)(rwin + (size_t)(x - sx) * 256 + g * 8);
            float4 r0 = rp[0], r1 = rp[1];
            s = l0.x * r0.x + l0.y * r0.y + l0.z * r0.z + l0.w * r0.w +
                l1.x * r1.x + l1.y * r1.y + l1.z * r1.z + l1.w * r1.w;
            s *= 0.125f;
        }
        outp[(size_t)d * PWp * ROW] = __float2bfloat16(s);
    }
}

// ---------------------------------------------------------------------------
// Mid conv, pipelined d-walk (r10/r13/r14 structure EXACTLY: 256 thr / 4
// waves, grid 512 = (w-quad, d-segment of 3), full-h 25 KB slices, 76 KB
// ring, 2 blocks/CU, dz-split async refill, co-tile-0 B-frags hoisted).
// Swizzle involution f(s)=s^((s>>3)&3) on global source; reads use
// slot=(hh*4+kg)^((hh>>1)&3). Verified r5/r6: 0 bank conflicts.
// ---------------------------------------------------------------------------
__global__ __launch_bounds__(256, 2) void conv_mid_kernel(
    const bf16* __restrict__ X, const bf16* __restrict__ Wb,
    const float* __restrict__ bias, bf16* __restrict__ Y) {
    __shared__ bf16 lds[3 * SLICE_E];
    int id   = blockIdx.x;
    int xcd  = id & 7;
    int r    = id >> 3;                  // 0..63
    int wq   = r & 31;
    int dseg = xcd * 2 + (r >> 5);       // blocks sharing slices land on same XCD
    int w0   = wq * 4;
    int d0   = dseg * 3;
    int tid  = threadIdx.x;
    int wv   = tid >> 6;
    int lane = tid & 63;
    int arow = lane & 15;
    int kg   = lane >> 4;

    auto stage = [&](int dslice, bf16* dst) {
#pragma unroll
        for (int row = 0; row < 6; ++row) {
            const bf16* base = X + ((size_t)dslice * PWp + (w0 + row)) * ROW;
            bf16* ldst = dst + row * ROW;
            int s = wv * 64 + lane;
            int gir = s ^ ((s >> 3) & 3);
            gload_lds16(base + gir * 8, ldst + wv * 512);
            if (tid < 8) {
                int s2 = 256 + lane;
                int gir2 = s2 ^ ((s2 >> 3) & 3);
                gload_lds16(base + gir2 * 8, ldst + 2048);
            }
        }
    };

    bf16* p0 = lds;
    bf16* p1 = lds + SLICE_E;
    bf16* p2 = lds + 2 * SLICE_E;
    stage(d0 + 0, p0);
    stage(d0 + 1, p1);
    stage(d0 + 2, p2);

    const short8* Wv = (const short8*)Wb;
    // Hoist co-tile-0 B-fragments for all 27 taps (108 VGPRs, layer-invariant)
    short8 B0[27];
#pragma unroll
    for (int tap = 0; tap < 27; ++tap)
        B0[tap] = Wv[tap * 128 + arow * 4 + kg];

    __syncthreads();

    float bv0 = bias[arow];
    float bv1 = bias[arow + 16];

    for (int i = 0; i < 3; ++i) {
        f32x4 acc[4][2] = {};

        // accumulate one dz-slice worth of taps from ring slot P
        auto compute_dz = [&](const bf16* P, int dz) {
#pragma unroll
            for (int dx = 0; dx < 3; ++dx) {
                const bf16* Ar = P + (wv + dx) * ROW;
#pragma unroll
                for (int dy = 0; dy < 3; ++dy) {
                    int tap = dz * 9 + dy * 3 + dx;
                    short8 b1 = Wv[tap * 128 + 64 + arow * 4 + kg];
                    int hh = arow + dy;
                    int s0 = (hh * 4 + kg) ^ ((hh >> 1) & 3);
#pragma unroll
                    for (int t = 0; t < 4; ++t) {
                        short8 a = *(const short8*)(Ar + s0 * 8 + t * 512);
                        acc[t][0] = __builtin_amdgcn_mfma_f32_16x16x32_bf16(
                            a, B0[tap], acc[t][0], 0, 0, 0);
                        acc[t][1] = __builtin_amdgcn_mfma_f32_16x16x32_bf16(
                            a, b1, acc[t][1], 0, 0, 0);
                    }
                }
            }
        };

        // Phase A: dz=0 -- sole reader of p0
        compute_dz(p0, 0);
        __syncthreads();                       // all waves done with p0
        if (i < 2) stage(d0 + i + 3, p0);      // async refill into freed slot
        // Phase B: dz=1,2 -- stage latency hides under this
        compute_dz(p1, 1);
        compute_dz(p2, 2);

        int d = d0 + i;
        bf16* Yp = Y + (((size_t)(d + 1) * PWp + (w0 + wv + 1))) * ROW + 32;
#pragma unroll
        for (int t = 0; t < 4; ++t)
#pragma unroll
            for (int rr = 0; rr < 4; ++rr) {
                int o = t * 16 + kg * 4 + rr;
                float v0 = acc[t][0][rr] + bv0;
                float v1 = acc[t][1][rr] + bv1;
                v0 = fmaxf(v0, 0.f) + 0.2f * fminf(v0, 0.f);
                v1 = fmaxf(v1, 0.f) + 0.2f * fminf(v1, 0.f);
                Yp[o * 32 + arow]      = __float2bfloat16(v0);
                Yp[o * 32 + arow + 16] = __float2bfloat16(v1);
            }
        __syncthreads();                       // vmcnt(0) drained here: slice landed
        bf16* tswap = p0; p0 = p1; p1 = p2; p2 = tswap;
    }
}

// ---------------------------------------------------------------------------
// Final conv (32ch -> 1), same structure; all 27 B-frags hoisted. fp32 out.
// ---------------------------------------------------------------------------
__global__ __launch_bounds__(256, 2) void conv_final_kernel(
    const bf16* __restrict__ X, const bf16* __restrict__ Wb,
    const float* __restrict__ bias, float* __restrict__ out) {
    __shared__ bf16 lds[3 * SLICE_E];
    int id   = blockIdx.x;
    int xcd  = id & 7;
    int r    = id >> 3;
    int wq   = r & 31;
    int dseg = xcd * 2 + (r >> 5);
    int w0   = wq * 4;
    int d0   = dseg * 3;
    int tid  = threadIdx.x;
    int wv   = tid >> 6;
    int lane = tid & 63;
    int arow = lane & 15;
    int kg   = lane >> 4;

    auto stage = [&](int dslice, bf16* dst) {
#pragma unroll
        for (int row = 0; row < 6; ++row) {
            const bf16* base = X + ((size_t)dslice * PWp + (w0 + row)) * ROW;
            bf16* ldst = dst + row * ROW;
            int s = wv * 64 + lane;
            int gir = s ^ ((s >> 3) & 3);
            gload_lds16(base + gir * 8, ldst + wv * 512);
            if (tid < 8) {
                int s2 = 256 + lane;
                int gir2 = s2 ^ ((s2 >> 3) & 3);
                gload_lds16(base + gir2 * 8, ldst + 2048);
            }
        }
    };

    bf16* p0 = lds;
    bf16* p1 = lds + SLICE_E;
    bf16* p2 = lds + 2 * SLICE_E;
    stage(d0 + 0, p0);
    stage(d0 + 1, p1);
    stage(d0 + 2, p2);

    const short8* Wv = (const short8*)Wb;
    short8 B0[27];
#pragma unroll
    for (int tap = 0; tap < 27; ++tap)
        B0[tap] = Wv[tap * 64 + arow * 4 + kg];

    __syncthreads();

    float bv = bias[0];

    for (int i = 0; i < 3; ++i) {
        f32x4 acc[4] = {};

        auto compute_dz = [&](const bf16* P, int dz) {
#pragma unroll
            for (int dx = 0; dx < 3; ++dx) {
                const bf16* Ar = P + (wv + dx) * ROW;
#pragma unroll
                for (int dy = 0; dy < 3; ++dy) {
                    int tap = dz * 9 + dy * 3 + dx;
                    int hh = arow + dy;
                    int s0 = (hh * 4 + kg) ^ ((hh >> 1) & 3);
#pragma unroll
                    for (int t = 0; t < 4; ++t) {
                        short8 a = *(const short8*)(Ar + s0 * 8 + t * 512);
                        acc[t] = __builtin_amdgcn_mfma_f32_16x16x32_bf16(
                            a, B0[tap], acc[t], 0, 0, 0);
                    }
                }
            }
        };

        compute_dz(p0, 0);
        __syncthreads();
        if (i < 2) stage(d0 + i + 3, p0);
        compute_dz(p1, 1);
        compute_dz(p2, 2);

        if (arow == 0) {
            int d = d0 + i;
#pragma unroll
            for (int t = 0; t < 4; ++t)
#pragma unroll
                for (int rr = 0; rr < 4; ++rr) {
                    int o = t * 16 + kg * 4 + rr;
                    out[((size_t)d * HH + o) * WW + (w0 + wv)] = acc[t][rr] + bv;
                }
        }
        __syncthreads();
        bf16* tswap = p0; p0 = p1; p1 = p2; p2 = tswap;
    }
}

// ---------------------------------------------------------------------------
// Launch
// ---------------------------------------------------------------------------
extern "C" void kernel_launch(void* const* d_in, const int* in_sizes, int n_in,
                              void* d_out, int out_size, void* d_ws, size_t ws_size,
                              hipStream_t stream) {
    const float* left  = (const float*)d_in[0];
    const float* right = (const float*)d_in[1];
    const float* w0 = (const float*)d_in[2];
    const float* b0 = (const float*)d_in[3];
    const float* w1 = (const float*)d_in[4];
    const float* b1 = (const float*)d_in[5];
    const float* w2 = (const float*)d_in[6];
    const float* b2 = (const float*)d_in[7];
    const float* w3 = (const float*)d_in[8];
    const float* b3 = (const float*)d_in[9];
    const float* wf = (const float*)d_in[10];
    const float* bf = (const float*)d_in[11];

    bf16* volA = (bf16*)d_ws;
    bf16* volB = volA + PVOL;
    bf16* wb0  = volB + PVOL;                 // 4 x 27648 contiguous
    bf16* wb1  = wb0 + 27648;
    bf16* wb2  = wb1 + 27648;
    bf16* wb3  = wb2 + 27648;
    bf16* wbf  = wb3 + 27648;                 // 13824 elems
    float* Lt  = (float*)(wbf + 13824 + 32);  // 16B-aligned
    float* Rt  = Lt + FEAT;

    transpose_feat_kernel<<<dim3(WW / 32, HH, 3), 256, 0, stream>>>(
        left, right, Lt, Rt, w0, w1, w2, w3, wf, wb0, wbf);

    build_vol_kernel<<<dim3(WW / 8, HH), 256, 0, stream>>>(Lt, Rt, volA, volB);

    int grid = 512;   // 32 w-quads x 16 d-segments, all-resident (2 blocks/CU)
    conv_mid_kernel<<<grid, 256, 0, stream>>>(volA, wb0, b0, volB);
    conv_mid_kernel<<<grid, 256, 0, stream>>>(volB, wb1, b1, volA);
    conv_mid_kernel<<<grid, 256, 0, stream>>>(volA, wb2, b2, volB);
    conv_mid_kernel<<<grid, 256, 0, stream>>>(volB, wb3, b3, volA);
    conv_final_kernel<<<grid, 256, 0, stream>>>(volA, wbf, bf, (float*)d_out);
}